// Round 4
// baseline (736.805 us; speedup 1.0000x reference)
//
#include <hip/hip_runtime.h>
#include <hip/hip_bf16.h>
#include <math.h>

// Problem constants:
//   B=4, Lq=4096, C=768, NH=12, d=64, NP=4, nl=1, H=W=64, Lin=4096, hid=192
#define B_    4
#define LQ    4096
#define CC    768
#define NH_   12
#define DH    64
#define NP_   4
#define HH    64
#define WW    64
#define HID   192
#define ROWS  (B_ * LQ)          // 16384
#define EPS_  1e-5f

typedef __bf16 bf16x8 __attribute__((ext_vector_type(8)));
typedef __bf16 bf16x4 __attribute__((ext_vector_type(4)));
typedef float  f32x4  __attribute__((ext_vector_type(4)));

// ---------------------------------------------------------------------------
// Batched weight prep: f32 [K,N] -> bf16 [Npad,K] transposed; rows [N,Npad) zero
// ---------------------------------------------------------------------------
struct PrepJob { const float* W; __bf16* Wt; int K; int N; int Npad; };
struct PrepJobs { PrepJob j[6]; };

__global__ __launch_bounds__(256)
void prep_all(PrepJobs jobs) {
    PrepJob job = jobs.j[blockIdx.z];
    int k0 = blockIdx.x * 64, n0 = blockIdx.y * 64;
    if (k0 >= job.K || n0 >= job.Npad) return;
    __shared__ float tile[64][65];
    int c = threadIdx.x & 63, r0 = threadIdx.x >> 6;
    #pragma unroll
    for (int i = 0; i < 16; ++i) {
        int kk = i * 4 + r0;
        float v = 0.f;
        if (k0 + kk < job.K && n0 + c < job.N) v = job.W[(size_t)(k0 + kk) * job.N + n0 + c];
        tile[kk][c] = v;
    }
    __syncthreads();
    #pragma unroll
    for (int i = 0; i < 16; ++i) {
        int nn = i * 4 + r0;
        if (n0 + nn < job.Npad && k0 + c < job.K)
            job.Wt[(size_t)(n0 + nn) * job.K + k0 + c] = (__bf16)tile[c][nn];
    }
}

// ---------------------------------------------------------------------------
// Reductions
// ---------------------------------------------------------------------------
__inline__ __device__ float wave_sum64(float v) {
    #pragma unroll
    for (int o = 32; o > 0; o >>= 1) v += __shfl_down(v, o, 64);
    return v;
}

// ---------------------------------------------------------------------------
// Fused dual LayerNorm (f32 in, bf16 out), float4 vectorized.
// blockIdx.y selects stream 0 (query) or 1 (feat). 256 thr, 192 active vec4.
// ---------------------------------------------------------------------------
__global__ __launch_bounds__(256)
void ln2_kernel(const float* __restrict__ x0, const float* __restrict__ g0,
                const float* __restrict__ b0, __bf16* __restrict__ y0,
                const float* __restrict__ x1, const float* __restrict__ g1,
                const float* __restrict__ b1, __bf16* __restrict__ y1) {
    int sel = blockIdx.y;
    const float* x = sel ? x1 : x0;
    const float* g = sel ? g1 : g0;
    const float* b = sel ? b1 : b0;
    __bf16* y = sel ? y1 : y0;
    int row = blockIdx.x;
    const float* xr = x + (size_t)row * CC;
    __bf16* yr = y + (size_t)row * CC;
    int t = threadIdx.x;
    f32x4 xv = {0.f, 0.f, 0.f, 0.f};
    if (t < 192) xv = *(const f32x4*)(xr + t * 4);
    float s  = xv[0] + xv[1] + xv[2] + xv[3];
    float s2 = xv[0]*xv[0] + xv[1]*xv[1] + xv[2]*xv[2] + xv[3]*xv[3];
    __shared__ float red[8];
    float ws = wave_sum64(s), ws2 = wave_sum64(s2);
    int w = t >> 6;
    if ((t & 63) == 0) { red[w] = ws; red[4 + w] = ws2; }
    __syncthreads();
    float S  = red[0] + red[1] + red[2] + red[3];
    float S2 = red[4] + red[5] + red[6] + red[7];
    float mean = S / CC;
    float inv  = rsqrtf(S2 / CC - mean * mean + EPS_);
    if (t < 192) {
        f32x4 gv = *(const f32x4*)(g + t * 4);
        f32x4 bv = *(const f32x4*)(b + t * 4);
        bf16x4 o;
        #pragma unroll
        for (int e = 0; e < 4; ++e)
            o[e] = (__bf16)((xv[e] - mean) * inv * gv[e] + bv[e]);
        *(bf16x4*)(yr + t * 4) = o;
    }
}

// ---------------------------------------------------------------------------
// LayerNorm, bf16 in -> bf16 out, bf16x8 vectorized (96 active threads of 256)
// ---------------------------------------------------------------------------
__global__ __launch_bounds__(256)
void ln_bf_kernel(const __bf16* __restrict__ x, const float* __restrict__ g,
                  const float* __restrict__ b, __bf16* __restrict__ y) {
    int row = blockIdx.x;
    const __bf16* xr = x + (size_t)row * CC;
    __bf16* yr = y + (size_t)row * CC;
    int t = threadIdx.x;
    float xv[8]; bf16x8 raw = {};
    if (t < 96) raw = *(const bf16x8*)(xr + t * 8);
    float s = 0.f, s2 = 0.f;
    #pragma unroll
    for (int e = 0; e < 8; ++e) { xv[e] = (float)raw[e]; s += xv[e]; s2 += xv[e]*xv[e]; }
    __shared__ float red[8];
    float ws = wave_sum64(s), ws2 = wave_sum64(s2);
    int w = t >> 6;
    if ((t & 63) == 0) { red[w] = ws; red[4 + w] = ws2; }
    __syncthreads();
    float S  = red[0] + red[1] + red[2] + red[3];
    float S2 = red[4] + red[5] + red[6] + red[7];
    float mean = S / CC;
    float inv  = rsqrtf(S2 / CC - mean * mean + EPS_);
    if (t < 96) {
        bf16x8 o;
        #pragma unroll
        for (int e = 0; e < 8; ++e)
            o[e] = (__bf16)((xv[e] - mean) * inv * g[t * 8 + e] + b[t * 8 + e]);
        *(bf16x8*)(yr + t * 8) = o;
    }
}

// ---------------------------------------------------------------------------
// Barrier-free direct-register bf16 MFMA GEMM, 64x64 tile per block.
// NO LDS, NO __syncthreads: wave w owns rows [w*16, w*16+16) (private A),
// B (weights, L2-resident) loaded per-wave global->reg. Compiler free to
// run loads ahead; waves fully independent -> TLP at wave granularity.
// XCD-aware swizzle (grids always %8==0 -> bijective).
// flags: 1 gelu, 2 out bf16, 4 res bf16
// ---------------------------------------------------------------------------
__global__ __launch_bounds__(256, 4)
void gemm_reg(const __bf16* __restrict__ A, const __bf16* __restrict__ Bt,
              const float* __restrict__ ba, int Nsplit, const float* __restrict__ bb,
              const void* __restrict__ res, void* __restrict__ out,
              int M, int K, int N, int flags) {
    int t = threadIdx.x;
    int lane = t & 63, wave = t >> 6;

    // XCD swizzle: contiguous chunk of 1/8th of the grid per XCD
    int nwg = gridDim.x * gridDim.y;
    int bid = blockIdx.y * gridDim.x + blockIdx.x;
    int swz = (bid & 7) * (nwg >> 3) + (bid >> 3);
    int bx = swz % gridDim.x, by = swz / gridDim.x;
    int bm = by * 64, bn = bx * 64;

    int rsel = lane & 15, kq = lane >> 4;

    // per-lane fragment pointers (16B-aligned)
    const __bf16* pA  = A  + (size_t)(bm + wave * 16 + rsel) * K + kq * 8;
    const __bf16* pB0 = Bt + (size_t)(bn + rsel)      * K + kq * 8;
    const __bf16* pB1 = pB0 + (size_t)16 * K;
    const __bf16* pB2 = pB0 + (size_t)32 * K;
    const __bf16* pB3 = pB0 + (size_t)48 * K;

    f32x4 acc[4] = {};

    #pragma unroll 6
    for (int k0 = 0; k0 < K; k0 += 32) {
        bf16x8 afr = *(const bf16x8*)(pA  + k0);
        bf16x8 b0  = *(const bf16x8*)(pB0 + k0);
        bf16x8 b1  = *(const bf16x8*)(pB1 + k0);
        bf16x8 b2  = *(const bf16x8*)(pB2 + k0);
        bf16x8 b3  = *(const bf16x8*)(pB3 + k0);
        acc[0] = __builtin_amdgcn_mfma_f32_16x16x32_bf16(afr, b0, acc[0], 0, 0, 0);
        acc[1] = __builtin_amdgcn_mfma_f32_16x16x32_bf16(afr, b1, acc[1], 0, 0, 0);
        acc[2] = __builtin_amdgcn_mfma_f32_16x16x32_bf16(afr, b2, acc[2], 0, 0, 0);
        acc[3] = __builtin_amdgcn_mfma_f32_16x16x32_bf16(afr, b3, acc[3], 0, 0, 0);
    }

    int rowq = lane >> 4;
    int do_gelu = flags & 1, out_bf = flags & 2, res_bf = flags & 4;
    #pragma unroll
    for (int j = 0; j < 4; ++j) {
        int c = bn + j * 16 + rsel;
        if (c < N) {
            float bias = (c < Nsplit) ? ba[c] : bb[c - Nsplit];
            #pragma unroll
            for (int r = 0; r < 4; ++r) {
                int m = bm + wave * 16 + rowq * 4 + r;
                float v = acc[j][r] + bias;
                if (do_gelu) v = 0.5f * v * (1.f + erff(v * 0.70710678118f));
                size_t oi = (size_t)m * N + c;
                if (res) v += res_bf ? (float)((const __bf16*)res)[oi]
                                     : ((const float*)res)[oi];
                if (out_bf) ((__bf16*)out)[oi] = (__bf16)v;
                else        ((float*)out)[oi]  = v;
            }
        }
    }
}

// ---------------------------------------------------------------------------
// Deformable sampling v3: one wave per (b,q,h).
//   lane = p*16 + g : p = sample point (0..3), g = channel group (4 bf16).
// Each lane: one coord chain, 4 in-lane corner loads (constant cx/cy).
// Butterfly (xor 16,32) sums points; lanes p==0 store bf16x4.
// ---------------------------------------------------------------------------
__global__ __launch_bounds__(256)
void sample_kernel(const __bf16* __restrict__ value, const float* __restrict__ offatt,
                   const float* __restrict__ refp, __bf16* __restrict__ out) {
    int wid  = blockIdx.x * 4 + (threadIdx.x >> 6);
    int lane = threadIdx.x & 63;
    int h  = wid % NH_;
    int bq = wid / NH_;
    int b  = bq / LQ;

    const float* oa = offatt + (size_t)bq * 144;
    float rx = refp[(size_t)bq * 2 + 0] * (float)WW - 0.5f;
    float ry = refp[(size_t)bq * 2 + 1] * (float)HH - 0.5f;

    // softmax over this head's 4 logits (wave-uniform -> s_loads)
    float l0 = oa[96 + h * 4 + 0], l1 = oa[96 + h * 4 + 1];
    float l2 = oa[96 + h * 4 + 2], l3 = oa[96 + h * 4 + 3];
    float mx = fmaxf(fmaxf(l0, l1), fmaxf(l2, l3));
    float e0 = __expf(l0 - mx), e1 = __expf(l1 - mx);
    float e2 = __expf(l2 - mx), e3 = __expf(l3 - mx);
    float rs = 1.f / (e0 + e1 + e2 + e3);

    int pp = lane >> 4;       // point id
    int g  = lane & 15;       // channel group
    float wpl = (pp == 0) ? e0 : (pp == 1) ? e1 : (pp == 2) ? e2 : e3;
    wpl *= rs;

    // per-lane point coords (8B vector load, divergent by pp)
    const float* oxy = oa + h * 8 + pp * 2;
    float x = rx + oxy[0];
    float y = ry + oxy[1];
    float x0f = floorf(x), y0f = floorf(y);
    float wx1 = x - x0f, wy1 = y - y0f;
    float wx0 = 1.f - wx1, wy0 = 1.f - wy1;
    int x0 = (int)x0f, y0 = (int)y0f;
    int x1 = x0 + 1, y1 = y0 + 1;
    // zero weights at OOB; address clamp via &63 (weight already 0 there)
    float mx0 = ((unsigned)x0 < (unsigned)WW) ? wx0 : 0.f;
    float mx1 = ((unsigned)x1 < (unsigned)WW) ? wx1 : 0.f;
    float my0 = (((unsigned)y0 < (unsigned)HH) ? wy0 : 0.f) * wpl;
    float my1 = (((unsigned)y1 < (unsigned)HH) ? wy1 : 0.f) * wpl;
    int xc0 = x0 & (WW - 1), xc1 = x1 & (WW - 1);
    int r0 = (y0 & (HH - 1)) << 6, r1 = (y1 & (HH - 1)) << 6;

    const __bf16* vbase = value + (size_t)b * (LQ * CC) + h * DH + g * 4;
    bf16x4 v00 = *(const bf16x4*)(vbase + (size_t)(r0 + xc0) * CC);
    bf16x4 v01 = *(const bf16x4*)(vbase + (size_t)(r0 + xc1) * CC);
    bf16x4 v10 = *(const bf16x4*)(vbase + (size_t)(r1 + xc0) * CC);
    bf16x4 v11 = *(const bf16x4*)(vbase + (size_t)(r1 + xc1) * CC);
    float w00 = mx0 * my0, w01 = mx1 * my0, w10 = mx0 * my1, w11 = mx1 * my1;

    f32x4 acc;
    #pragma unroll
    for (int e = 0; e < 4; ++e)
        acc[e] = w00 * (float)v00[e] + w01 * (float)v01[e]
               + w10 * (float)v10[e] + w11 * (float)v11[e];

    #pragma unroll
    for (int e = 0; e < 4; ++e) {
        acc[e] += __shfl_xor(acc[e], 16, 64);
        acc[e] += __shfl_xor(acc[e], 32, 64);
    }
    if (pp == 0) {
        bf16x4 o;
        o[0] = (__bf16)acc[0]; o[1] = (__bf16)acc[1];
        o[2] = (__bf16)acc[2]; o[3] = (__bf16)acc[3];
        *(bf16x4*)(out + (size_t)bq * CC + h * DH + g * 4) = o;
    }
}

// ---------------------------------------------------------------------------
// Launch
// ---------------------------------------------------------------------------
extern "C" void kernel_launch(void* const* d_in, const int* in_sizes, int n_in,
                              void* d_out, int out_size, void* d_ws, size_t ws_size,
                              hipStream_t stream) {
    const float* query = (const float*)d_in[0];
    const float* refp  = (const float*)d_in[1];
    const float* feat  = (const float*)d_in[2];
    const float* qn_g  = (const float*)d_in[7];
    const float* qn_b  = (const float*)d_in[8];
    const float* fn_g  = (const float*)d_in[9];
    const float* fn_b  = (const float*)d_in[10];
    const float* Wv    = (const float*)d_in[11];
    const float* bv    = (const float*)d_in[12];
    const float* Woff  = (const float*)d_in[13];
    const float* boff  = (const float*)d_in[14];
    const float* Watt  = (const float*)d_in[15];
    const float* batt  = (const float*)d_in[16];
    const float* Wout  = (const float*)d_in[17];
    const float* bout  = (const float*)d_in[18];
    const float* ffn_g = (const float*)d_in[19];
    const float* ffn_b = (const float*)d_in[20];
    const float* W1    = (const float*)d_in[21];
    const float* b1    = (const float*)d_in[22];
    const float* W2    = (const float*)d_in[23];
    const float* b2    = (const float*)d_in[24];
    float* out = (float*)d_out;

    // workspace layout (byte offsets)
    char* ws = (char*)d_ws;
    __bf16* WvT    = (__bf16*)(ws + 0);            // 1179648
    __bf16* WcombT = (__bf16*)(ws + 1179648);      // 192x768x2 = 294912 (slot 393216)
    __bf16* WoutT  = (__bf16*)(ws + 1572864);      // 1179648
    __bf16* W1T    = (__bf16*)(ws + 2752512);      // 192x768x2 = 294912 (slot 393216)
    __bf16* W2T    = (__bf16*)(ws + 3145728);      // 294912
    float*  offatt_f = (float*)(ws + 3670016);     // 9437184
    __bf16* h1_bf    = (__bf16*)offatt_f;          // reuse
    __bf16* bufA     = (__bf16*)(ws + 13107200);   // 25165824
    __bf16* qn_bf    = bufA;
    __bf16* value_bf = bufA;
    __bf16* bufB     = (__bf16*)(ws + 38273024);   // 25165824
    __bf16* fn_bf    = bufB;
    __bf16* samp_bf  = bufB;
    __bf16* h_bf     = bufB;
    __bf16* attn_bf  = (__bf16*)(ws + 63438848);   // 25165824

    dim3 blk(256);

    // 0. batched weight prep (one launch)
    PrepJobs jobs;
    jobs.j[0] = {Wv,   WvT,             768, 768, 768};
    jobs.j[1] = {Woff, WcombT,          768,  96,  96};
    jobs.j[2] = {Watt, WcombT + 96*768, 768,  48,  96};  // comb rows 96..191 (144..191 zero)
    jobs.j[3] = {Wout, WoutT,           768, 768, 768};
    jobs.j[4] = {W1,   W1T,             768, 192, 192};
    jobs.j[5] = {W2,   W2T,             192, 768, 768};
    prep_all<<<dim3(12, 12, 6), blk, 0, stream>>>(jobs);

    // 1. both input LayerNorms in one launch
    ln2_kernel<<<dim3(ROWS, 2), blk, 0, stream>>>(query, qn_g, qn_b, qn_bf,
                                                  feat,  fn_g, fn_b, fn_bf);

    // 2. offatt = qn @ [Woff|Watt] (N=144, Npad=192, f32 out)
    gemm_reg<<<dim3(3, ROWS / 64), blk, 0, stream>>>(
        qn_bf, WcombT, boff, 96, batt, nullptr, offatt_f, ROWS, CC, 144, 0);
    // 3. value = fn @ Wv + bv (bf16 out)
    gemm_reg<<<dim3(12, ROWS / 64), blk, 0, stream>>>(
        fn_bf, WvT, bv, CC, nullptr, nullptr, value_bf, ROWS, CC, CC, 2);
    // 4. deformable sampling -> bf16
    sample_kernel<<<ROWS * NH_ / 4, blk, 0, stream>>>(value_bf, offatt_f, refp, samp_bf);
    // 5. attnres = query + samp @ Wout + bout (bf16 out)
    gemm_reg<<<dim3(12, ROWS / 64), blk, 0, stream>>>(
        samp_bf, WoutT, bout, CC, nullptr, query, attn_bf, ROWS, CC, CC, 2);
    // 6. h = LN(attnres) -> bf16
    ln_bf_kernel<<<ROWS, blk, 0, stream>>>(attn_bf, ffn_g, ffn_b, h_bf);
    // 7. h1 = gelu(h @ W1 + b1) -> bf16 (N=192)
    gemm_reg<<<dim3(3, ROWS / 64), blk, 0, stream>>>(
        h_bf, W1T, b1, HID, nullptr, nullptr, h1_bf, ROWS, CC, HID, 1 | 2);
    // 8. out = attnres + h1 @ W2 + b2 (K=192, f32 out, bf16 res)
    gemm_reg<<<dim3(12, ROWS / 64), blk, 0, stream>>>(
        h1_bf, W2T, b2, CC, nullptr, attn_bf, out, ROWS, HID, CC, 4);
}

// Round 5
// 469.886 us; speedup vs baseline: 1.5681x; 1.5681x over previous
//
#include <hip/hip_runtime.h>
#include <hip/hip_bf16.h>
#include <math.h>

// Problem constants:
//   B=4, Lq=4096, C=768, NH=12, d=64, NP=4, nl=1, H=W=64, Lin=4096, hid=192
#define B_    4
#define LQ    4096
#define CC    768
#define NH_   12
#define DH    64
#define NP_   4
#define HH    64
#define WW    64
#define HID   192
#define ROWS  (B_ * LQ)          // 16384
#define EPS_  1e-5f

typedef __bf16 bf16x8 __attribute__((ext_vector_type(8)));
typedef __bf16 bf16x4 __attribute__((ext_vector_type(4)));
typedef float  f32x4  __attribute__((ext_vector_type(4)));

typedef __attribute__((address_space(3))) void* lds_vp;
typedef const __attribute__((address_space(1))) void* gbl_vp;

// ---------------------------------------------------------------------------
// Batched weight prep: f32 [K,N] -> bf16 [Npad,K] transposed; rows [N,Npad) zero
// ---------------------------------------------------------------------------
struct PrepJob { const float* W; __bf16* Wt; int K; int N; int Npad; };
struct PrepJobs { PrepJob j[6]; };

__global__ __launch_bounds__(256)
void prep_all(PrepJobs jobs) {
    PrepJob job = jobs.j[blockIdx.z];
    int k0 = blockIdx.x * 64, n0 = blockIdx.y * 64;
    if (k0 >= job.K || n0 >= job.Npad) return;
    __shared__ float tile[64][65];
    int c = threadIdx.x & 63, r0 = threadIdx.x >> 6;
    #pragma unroll
    for (int i = 0; i < 16; ++i) {
        int kk = i * 4 + r0;
        float v = 0.f;
        if (k0 + kk < job.K && n0 + c < job.N) v = job.W[(size_t)(k0 + kk) * job.N + n0 + c];
        tile[kk][c] = v;
    }
    __syncthreads();
    #pragma unroll
    for (int i = 0; i < 16; ++i) {
        int nn = i * 4 + r0;
        if (n0 + nn < job.Npad && k0 + c < job.K)
            job.Wt[(size_t)(n0 + nn) * job.K + k0 + c] = (__bf16)tile[c][nn];
    }
}

// ---------------------------------------------------------------------------
// Reductions
// ---------------------------------------------------------------------------
__inline__ __device__ float wave_sum64(float v) {
    #pragma unroll
    for (int o = 32; o > 0; o >>= 1) v += __shfl_down(v, o, 64);
    return v;
}

// ---------------------------------------------------------------------------
// Fused dual LayerNorm (f32 in, bf16 out), float4 vectorized.
// ---------------------------------------------------------------------------
__global__ __launch_bounds__(256)
void ln2_kernel(const float* __restrict__ x0, const float* __restrict__ g0,
                const float* __restrict__ b0, __bf16* __restrict__ y0,
                const float* __restrict__ x1, const float* __restrict__ g1,
                const float* __restrict__ b1, __bf16* __restrict__ y1) {
    int sel = blockIdx.y;
    const float* x = sel ? x1 : x0;
    const float* g = sel ? g1 : g0;
    const float* b = sel ? b1 : b0;
    __bf16* y = sel ? y1 : y0;
    int row = blockIdx.x;
    const float* xr = x + (size_t)row * CC;
    __bf16* yr = y + (size_t)row * CC;
    int t = threadIdx.x;
    f32x4 xv = {0.f, 0.f, 0.f, 0.f};
    if (t < 192) xv = *(const f32x4*)(xr + t * 4);
    float s  = xv[0] + xv[1] + xv[2] + xv[3];
    float s2 = xv[0]*xv[0] + xv[1]*xv[1] + xv[2]*xv[2] + xv[3]*xv[3];
    __shared__ float red[8];
    float ws = wave_sum64(s), ws2 = wave_sum64(s2);
    int w = t >> 6;
    if ((t & 63) == 0) { red[w] = ws; red[4 + w] = ws2; }
    __syncthreads();
    float S  = red[0] + red[1] + red[2] + red[3];
    float S2 = red[4] + red[5] + red[6] + red[7];
    float mean = S / CC;
    float inv  = rsqrtf(S2 / CC - mean * mean + EPS_);
    if (t < 192) {
        f32x4 gv = *(const f32x4*)(g + t * 4);
        f32x4 bv = *(const f32x4*)(b + t * 4);
        bf16x4 o;
        #pragma unroll
        for (int e = 0; e < 4; ++e)
            o[e] = (__bf16)((xv[e] - mean) * inv * gv[e] + bv[e]);
        *(bf16x4*)(yr + t * 4) = o;
    }
}

// ---------------------------------------------------------------------------
// LayerNorm, bf16 in -> bf16 out, bf16x8 vectorized (96 active threads of 256)
// ---------------------------------------------------------------------------
__global__ __launch_bounds__(256)
void ln_bf_kernel(const __bf16* __restrict__ x, const float* __restrict__ g,
                  const float* __restrict__ b, __bf16* __restrict__ y) {
    int row = blockIdx.x;
    const __bf16* xr = x + (size_t)row * CC;
    __bf16* yr = y + (size_t)row * CC;
    int t = threadIdx.x;
    float xv[8]; bf16x8 raw = {};
    if (t < 96) raw = *(const bf16x8*)(xr + t * 8);
    float s = 0.f, s2 = 0.f;
    #pragma unroll
    for (int e = 0; e < 8; ++e) { xv[e] = (float)raw[e]; s += xv[e]; s2 += xv[e]*xv[e]; }
    __shared__ float red[8];
    float ws = wave_sum64(s), ws2 = wave_sum64(s2);
    int w = t >> 6;
    if ((t & 63) == 0) { red[w] = ws; red[4 + w] = ws2; }
    __syncthreads();
    float S  = red[0] + red[1] + red[2] + red[3];
    float S2 = red[4] + red[5] + red[6] + red[7];
    float mean = S / CC;
    float inv  = rsqrtf(S2 / CC - mean * mean + EPS_);
    if (t < 96) {
        bf16x8 o;
        #pragma unroll
        for (int e = 0; e < 8; ++e)
            o[e] = (__bf16)((xv[e] - mean) * inv * g[t * 8 + e] + b[t * 8 + e]);
        *(bf16x8*)(yr + t * 8) = o;
    }
}

// ---------------------------------------------------------------------------
// 256x256-tile bf16 MFMA GEMM (big-N: N % 256 == 0, M % 256 == 0).
// 8 waves (512 thr), BK=64, 128 KB double-buffered LDS, counted vmcnt(8),
// raw s_barrier. 3-bit chunk-XOR swizzle (global-source pre-swizzled, read
// side applies same XOR) -> <=2-way bank aliasing on 128 B rows.
// Staged volume: A x (N/256) + B x (M/256)  (~100 MB for the 768-col GEMMs
// vs ~300-590 MB for 64/128 tiles) — attacks the per-block delivery choke.
// flags: 2 out bf16, 4 res bf16 (res f32 otherwise)
// ---------------------------------------------------------------------------
__global__ __launch_bounds__(512, 2)
void gemm256(const __bf16* __restrict__ A, const __bf16* __restrict__ Bt,
             const float* __restrict__ ba, const void* __restrict__ res,
             void* __restrict__ out, int M, int K, int N, int flags) {
    __shared__ __bf16 As[2][256 * 64];
    __shared__ __bf16 Bs[2][256 * 64];

    int t = threadIdx.x;
    int lane = t & 63, wave = t >> 6;

    // XCD swizzle (grid = 192 blocks, %8==0 -> bijective)
    int nwg = gridDim.x * gridDim.y;
    int bid = blockIdx.y * gridDim.x + blockIdx.x;
    int swz = (bid & 7) * (nwg >> 3) + (bid >> 3);
    int bx = swz % gridDim.x, by = swz / gridDim.x;
    int bm = by * 256, bn = bx * 256;

    int wm = wave >> 2, wn = wave & 3;          // 2 x 4 wave grid
    int rsel = lane & 15, kq = lane >> 4;

    f32x4 acc[8][4] = {};

    // staging: thread t covers rows (t>>3)+64i, chunk position p=t&7 of the
    // 128 B row; global chunk c = p ^ ((row>>1)&7)  (inverse-swizzled source,
    // linear LDS dest as required by global_load_lds)
    int srow = t >> 3, p = t & 7;
    const __bf16* aS[4]; const __bf16* bS[4];
    #pragma unroll
    for (int i = 0; i < 4; ++i) {
        int r = srow + 64 * i;
        int c = p ^ ((r >> 1) & 7);
        aS[i] = A  + (size_t)(bm + r) * K + c * 8;
        bS[i] = Bt + (size_t)(bn + r) * K + c * 8;
    }

    #define STAGE(bi, kt) do {                                                                  \
        int ko_ = (kt) * 64;                                                                    \
        _Pragma("unroll")                                                                       \
        for (int i = 0; i < 4; ++i) {                                                           \
            __builtin_amdgcn_global_load_lds((gbl_vp)(aS[i] + ko_),                             \
                (lds_vp)&As[bi][t * 8 + i * 4096], 16, 0, 0);                                   \
            __builtin_amdgcn_global_load_lds((gbl_vp)(bS[i] + ko_),                             \
                (lds_vp)&Bs[bi][t * 8 + i * 4096], 16, 0, 0);                                   \
        }                                                                                       \
    } while (0)

    #define COMPUTE(bi) do {                                                                    \
        _Pragma("unroll")                                                                       \
        for (int h = 0; h < 2; ++h) {                                                           \
            bf16x8 afr[8], bfr[4];                                                              \
            _Pragma("unroll")                                                                   \
            for (int i = 0; i < 8; ++i) {                                                       \
                int r = wm * 128 + rsel + i * 16;                                               \
                afr[i] = *(const bf16x8*)&As[bi][r * 64 + (((h * 4 + kq) ^ ((r >> 1) & 7)) * 8)]; \
            }                                                                                   \
            _Pragma("unroll")                                                                   \
            for (int j = 0; j < 4; ++j) {                                                       \
                int n = wn * 64 + rsel + j * 16;                                                \
                bfr[j] = *(const bf16x8*)&Bs[bi][n * 64 + (((h * 4 + kq) ^ ((n >> 1) & 7)) * 8)]; \
            }                                                                                   \
            _Pragma("unroll")                                                                   \
            for (int i = 0; i < 8; ++i)                                                         \
                _Pragma("unroll")                                                               \
                for (int j = 0; j < 4; ++j)                                                     \
                    acc[i][j] = __builtin_amdgcn_mfma_f32_16x16x32_bf16(afr[i], bfr[j], acc[i][j], 0, 0, 0); \
        }                                                                                       \
    } while (0)

    int nt = K >> 6;   // K/64: 12 (K=768) or 3 (K=192)
    STAGE(0, 0);
    STAGE(1, 1);
    for (int tt = 0; tt < nt; ++tt) {
        int cur = tt & 1;
        // wait tile tt's 8 loads; tile tt+1's 8 stay in flight across barrier
        if (tt < nt - 1) asm volatile("s_waitcnt vmcnt(8)\n\ts_barrier" ::: "memory");
        else             asm volatile("s_waitcnt vmcnt(0)\n\ts_barrier" ::: "memory");
        COMPUTE(cur);
        asm volatile("s_waitcnt lgkmcnt(0)\n\ts_barrier" ::: "memory");
        if (tt + 2 < nt) STAGE(cur, tt + 2);
    }

    #undef STAGE
    #undef COMPUTE

    int rowq = lane >> 4;
    int out_bf = flags & 2, res_bf = flags & 4;
    #pragma unroll
    for (int j = 0; j < 4; ++j) {
        int c = bn + wn * 64 + j * 16 + rsel;
        float bias = ba[c];
        #pragma unroll
        for (int i = 0; i < 8; ++i) {
            #pragma unroll
            for (int r = 0; r < 4; ++r) {
                int m = bm + wm * 128 + i * 16 + rowq * 4 + r;
                float v = acc[i][j][r] + bias;
                size_t oi = (size_t)m * N + c;
                if (res) v += res_bf ? (float)((const __bf16*)res)[oi]
                                     : ((const float*)res)[oi];
                if (out_bf) ((__bf16*)out)[oi] = (__bf16)v;
                else        ((float*)out)[oi]  = v;
            }
        }
    }
}

// ---------------------------------------------------------------------------
// 64x64-tile GEMM for small N (144/192): 2-buffer LDS, counted vmcnt,
// XCD swizzle. flags: 1 gelu, 2 out bf16, 4 res bf16  (round-3 version)
// ---------------------------------------------------------------------------
__global__ __launch_bounds__(256, 8)
void gemm64(const __bf16* __restrict__ A, const __bf16* __restrict__ Bt,
            const float* __restrict__ ba, int Nsplit, const float* __restrict__ bb,
            const void* __restrict__ res, void* __restrict__ out,
            int M, int K, int N, int flags) {
    __shared__ __bf16 As[2][64 * 32];
    __shared__ __bf16 Bs[2][64 * 32];

    int t = threadIdx.x;
    int lane = t & 63, wave = t >> 6;

    int nwg = gridDim.x * gridDim.y;
    int bid = blockIdx.y * gridDim.x + blockIdx.x;
    int swz = (bid & 7) * (nwg >> 3) + (bid >> 3);
    int bx = swz % gridDim.x, by = swz / gridDim.x;
    int bm = by * 64, bn = bx * 64;

    f32x4 acc[4] = {};

    int row0 = t >> 2, kc0 = (t & 3) ^ ((row0 >> 1) & 3);
    const __bf16* a0 = A  + (size_t)(bm + row0) * K + kc0 * 8;
    const __bf16* b0 = Bt + (size_t)(bn + row0) * K + kc0 * 8;

    int rbase = wave * 16 + (lane & 15);
    int nbase = lane & 15;
    int kq = lane >> 4;

    #define STAGE(bi, kt) do {                                                                   \
        int koff_ = (kt) * 32;                                                                   \
        __builtin_amdgcn_global_load_lds((gbl_vp)(a0 + koff_), (lds_vp)&As[bi][t * 8], 16, 0, 0); \
        __builtin_amdgcn_global_load_lds((gbl_vp)(b0 + koff_), (lds_vp)&Bs[bi][t * 8], 16, 0, 0); \
    } while (0)

    #define COMPUTE(bi) do {                                                                     \
        bf16x8 afr = *(const bf16x8*)&As[bi][rbase * 32 + ((kq ^ ((rbase >> 1) & 3)) * 8)];      \
        _Pragma("unroll")                                                                        \
        for (int j = 0; j < 4; ++j) {                                                            \
            int n = nbase + j * 16;                                                              \
            bf16x8 bfr = *(const bf16x8*)&Bs[bi][n * 32 + ((kq ^ ((n >> 1) & 3)) * 8)];          \
            acc[j] = __builtin_amdgcn_mfma_f32_16x16x32_bf16(afr, bfr, acc[j], 0, 0, 0);         \
        }                                                                                        \
    } while (0)

    int nt = K >> 5;
    STAGE(0, 0);
    STAGE(1, 1);
    for (int tt = 0; tt < nt; ++tt) {
        int cur = tt & 1;
        if (tt < nt - 1) asm volatile("s_waitcnt vmcnt(2)\n\ts_barrier" ::: "memory");
        else             asm volatile("s_waitcnt vmcnt(0)\n\ts_barrier" ::: "memory");
        COMPUTE(cur);
        asm volatile("s_waitcnt lgkmcnt(0)\n\ts_barrier" ::: "memory");
        if (tt + 2 < nt) STAGE(cur, tt + 2);
    }

    #undef STAGE
    #undef COMPUTE

    int rowq = lane >> 4;
    int do_gelu = flags & 1, out_bf = flags & 2;
    #pragma unroll
    for (int r = 0; r < 4; ++r) {
        int m = bm + wave * 16 + rowq * 4 + r;
        #pragma unroll
        for (int j = 0; j < 4; ++j) {
            int c = bn + j * 16 + (lane & 15);
            if (c < N) {
                float v = acc[j][r] + ((c < Nsplit) ? ba[c] : bb[c - Nsplit]);
                if (do_gelu) v = 0.5f * v * (1.f + erff(v * 0.70710678118f));
                size_t oi = (size_t)m * N + c;
                if (out_bf) ((__bf16*)out)[oi] = (__bf16)v;
                else        ((float*)out)[oi]  = v;
            }
        }
    }
}

// ---------------------------------------------------------------------------
// Deformable sampling v3: one wave per (b,q,h).
// ---------------------------------------------------------------------------
__global__ __launch_bounds__(256)
void sample_kernel(const __bf16* __restrict__ value, const float* __restrict__ offatt,
                   const float* __restrict__ refp, __bf16* __restrict__ out) {
    int wid  = blockIdx.x * 4 + (threadIdx.x >> 6);
    int lane = threadIdx.x & 63;
    int h  = wid % NH_;
    int bq = wid / NH_;
    int b  = bq / LQ;

    const float* oa = offatt + (size_t)bq * 144;
    float rx = refp[(size_t)bq * 2 + 0] * (float)WW - 0.5f;
    float ry = refp[(size_t)bq * 2 + 1] * (float)HH - 0.5f;

    float l0 = oa[96 + h * 4 + 0], l1 = oa[96 + h * 4 + 1];
    float l2 = oa[96 + h * 4 + 2], l3 = oa[96 + h * 4 + 3];
    float mx = fmaxf(fmaxf(l0, l1), fmaxf(l2, l3));
    float e0 = __expf(l0 - mx), e1 = __expf(l1 - mx);
    float e2 = __expf(l2 - mx), e3 = __expf(l3 - mx);
    float rs = 1.f / (e0 + e1 + e2 + e3);

    int pp = lane >> 4;       // point id
    int g  = lane & 15;       // channel group
    float wpl = (pp == 0) ? e0 : (pp == 1) ? e1 : (pp == 2) ? e2 : e3;
    wpl *= rs;

    const float* oxy = oa + h * 8 + pp * 2;
    float x = rx + oxy[0];
    float y = ry + oxy[1];
    float x0f = floorf(x), y0f = floorf(y);
    float wx1 = x - x0f, wy1 = y - y0f;
    float wx0 = 1.f - wx1, wy0 = 1.f - wy1;
    int x0 = (int)x0f, y0 = (int)y0f;
    int x1 = x0 + 1, y1 = y0 + 1;
    float mx0 = ((unsigned)x0 < (unsigned)WW) ? wx0 : 0.f;
    float mx1 = ((unsigned)x1 < (unsigned)WW) ? wx1 : 0.f;
    float my0 = (((unsigned)y0 < (unsigned)HH) ? wy0 : 0.f) * wpl;
    float my1 = (((unsigned)y1 < (unsigned)HH) ? wy1 : 0.f) * wpl;
    int xc0 = x0 & (WW - 1), xc1 = x1 & (WW - 1);
    int r0 = (y0 & (HH - 1)) << 6, r1 = (y1 & (HH - 1)) << 6;

    const __bf16* vbase = value + (size_t)b * (LQ * CC) + h * DH + g * 4;
    bf16x4 v00 = *(const bf16x4*)(vbase + (size_t)(r0 + xc0) * CC);
    bf16x4 v01 = *(const bf16x4*)(vbase + (size_t)(r0 + xc1) * CC);
    bf16x4 v10 = *(const bf16x4*)(vbase + (size_t)(r1 + xc0) * CC);
    bf16x4 v11 = *(const bf16x4*)(vbase + (size_t)(r1 + xc1) * CC);
    float w00 = mx0 * my0, w01 = mx1 * my0, w10 = mx0 * my1, w11 = mx1 * my1;

    f32x4 acc;
    #pragma unroll
    for (int e = 0; e < 4; ++e)
        acc[e] = w00 * (float)v00[e] + w01 * (float)v01[e]
               + w10 * (float)v10[e] + w11 * (float)v11[e];

    #pragma unroll
    for (int e = 0; e < 4; ++e) {
        acc[e] += __shfl_xor(acc[e], 16, 64);
        acc[e] += __shfl_xor(acc[e], 32, 64);
    }
    if (pp == 0) {
        bf16x4 o;
        o[0] = (__bf16)acc[0]; o[1] = (__bf16)acc[1];
        o[2] = (__bf16)acc[2]; o[3] = (__bf16)acc[3];
        *(bf16x4*)(out + (size_t)bq * CC + h * DH + g * 4) = o;
    }
}

// ---------------------------------------------------------------------------
// Launch
// ---------------------------------------------------------------------------
extern "C" void kernel_launch(void* const* d_in, const int* in_sizes, int n_in,
                              void* d_out, int out_size, void* d_ws, size_t ws_size,
                              hipStream_t stream) {
    const float* query = (const float*)d_in[0];
    const float* refp  = (const float*)d_in[1];
    const float* feat  = (const float*)d_in[2];
    const float* qn_g  = (const float*)d_in[7];
    const float* qn_b  = (const float*)d_in[8];
    const float* fn_g  = (const float*)d_in[9];
    const float* fn_b  = (const float*)d_in[10];
    const float* Wv    = (const float*)d_in[11];
    const float* bv    = (const float*)d_in[12];
    const float* Woff  = (const float*)d_in[13];
    const float* boff  = (const float*)d_in[14];
    const float* Watt  = (const float*)d_in[15];
    const float* batt  = (const float*)d_in[16];
    const float* Wout  = (const float*)d_in[17];
    const float* bout  = (const float*)d_in[18];
    const float* ffn_g = (const float*)d_in[19];
    const float* ffn_b = (const float*)d_in[20];
    const float* W1    = (const float*)d_in[21];
    const float* b1    = (const float*)d_in[22];
    const float* W2    = (const float*)d_in[23];
    const float* b2    = (const float*)d_in[24];
    float* out = (float*)d_out;

    // workspace layout (byte offsets)
    char* ws = (char*)d_ws;
    __bf16* WvT    = (__bf16*)(ws + 0);            // 1179648
    __bf16* WcombT = (__bf16*)(ws + 1179648);      // 192x768x2 = 294912 (slot 393216)
    __bf16* WoutT  = (__bf16*)(ws + 1572864);      // 1179648
    __bf16* W1T    = (__bf16*)(ws + 2752512);      // 192x768x2 = 294912 (slot 393216)
    __bf16* W2T    = (__bf16*)(ws + 3145728);      // 294912
    float*  offatt_f = (float*)(ws + 3670016);     // 9437184
    __bf16* h1_bf    = (__bf16*)offatt_f;          // reuse
    __bf16* bufA     = (__bf16*)(ws + 13107200);   // 25165824
    __bf16* qn_bf    = bufA;
    __bf16* value_bf = bufA;
    __bf16* bufB     = (__bf16*)(ws + 38273024);   // 25165824
    __bf16* fn_bf    = bufB;
    __bf16* samp_bf  = bufB;
    __bf16* h_bf     = bufB;
    __bf16* attn_bf  = (__bf16*)(ws + 63438848);   // 25165824

    dim3 blk(256);

    // 0. batched weight prep (one launch)
    PrepJobs jobs;
    jobs.j[0] = {Wv,   WvT,             768, 768, 768};
    jobs.j[1] = {Woff, WcombT,          768,  96,  96};
    jobs.j[2] = {Watt, WcombT + 96*768, 768,  48,  96};  // comb rows 96..191 (144..191 zero)
    jobs.j[3] = {Wout, WoutT,           768, 768, 768};
    jobs.j[4] = {W1,   W1T,             768, 192, 192};
    jobs.j[5] = {W2,   W2T,             192, 768, 768};
    prep_all<<<dim3(12, 12, 6), blk, 0, stream>>>(jobs);

    // 1. both input LayerNorms in one launch
    ln2_kernel<<<dim3(ROWS, 2), blk, 0, stream>>>(query, qn_g, qn_b, qn_bf,
                                                  feat,  fn_g, fn_b, fn_bf);

    // 2. offatt = qn @ [Woff|Watt] (N=144, Npad=192, f32 out)
    gemm64<<<dim3(3, ROWS / 64), blk, 0, stream>>>(
        qn_bf, WcombT, boff, 96, batt, nullptr, offatt_f, ROWS, CC, 144, 0);
    // 3. value = fn @ Wv + bv (bf16 out) — 256x256 tiles
    gemm256<<<dim3(3, ROWS / 256), dim3(512), 0, stream>>>(
        fn_bf, WvT, bv, nullptr, value_bf, ROWS, CC, CC, 2);
    // 4. deformable sampling -> bf16
    sample_kernel<<<ROWS * NH_ / 4, blk, 0, stream>>>(value_bf, offatt_f, refp, samp_bf);
    // 5. attnres = query + samp @ Wout + bout (bf16 out, f32 res)
    gemm256<<<dim3(3, ROWS / 256), dim3(512), 0, stream>>>(
        samp_bf, WoutT, bout, query, attn_bf, ROWS, CC, CC, 2);
    // 6. h = LN(attnres) -> bf16
    ln_bf_kernel<<<ROWS, blk, 0, stream>>>(attn_bf, ffn_g, ffn_b, h_bf);
    // 7. h1 = gelu(h @ W1 + b1) -> bf16 (N=192)
    gemm64<<<dim3(3, ROWS / 64), blk, 0, stream>>>(
        h_bf, W1T, b1, HID, nullptr, nullptr, h1_bf, ROWS, CC, HID, 1 | 2);
    // 8. out = attnres + h1 @ W2 + b2 (K=192, f32 out, bf16 res)
    gemm256<<<dim3(3, ROWS / 256), dim3(512), 0, stream>>>(
        h1_bf, W2T, b2, attn_bf, out, ROWS, HID, CC, 4);
}

// Round 6
// 427.162 us; speedup vs baseline: 1.7249x; 1.1000x over previous
//
#include <hip/hip_runtime.h>
#include <hip/hip_bf16.h>
#include <math.h>

// Problem constants:
//   B=4, Lq=4096, C=768, NH=12, d=64, NP=4, nl=1, H=W=64, Lin=4096, hid=192
#define B_    4
#define LQ    4096
#define CC    768
#define NH_   12
#define DH    64
#define NP_   4
#define HH    64
#define WW    64
#define HID   192
#define ROWS  (B_ * LQ)          // 16384
#define EPS_  1e-5f

typedef __bf16 bf16x8 __attribute__((ext_vector_type(8)));
typedef __bf16 bf16x4 __attribute__((ext_vector_type(4)));
typedef float  f32x4  __attribute__((ext_vector_type(4)));

typedef __attribute__((address_space(3))) void* lds_vp;
typedef const __attribute__((address_space(1))) void* gbl_vp;

// ---------------------------------------------------------------------------
// Weight prep jobs: f32 [K,N] -> bf16 [Npad,K] transposed; rows [N,Npad) zero
// ---------------------------------------------------------------------------
struct PrepJob { const float* W; __bf16* Wt; int K; int N; int Npad; };
struct PrepJobs { PrepJob j[6]; };

// ---------------------------------------------------------------------------
// Reductions
// ---------------------------------------------------------------------------
__inline__ __device__ float wave_sum64(float v) {
    #pragma unroll
    for (int o = 32; o > 0; o >>= 1) v += __shfl_down(v, o, 64);
    return v;
}

// ---------------------------------------------------------------------------
// Merged launch: dual LayerNorm (f32 in, bf16 out) + weight prep.
// blocks [0, 2*ROWS): LN rows (sel = bx >= ROWS); blocks [2*ROWS, +864): prep
// tiles (144 per job x 6 jobs, early-out on overhang).
// ---------------------------------------------------------------------------
__global__ __launch_bounds__(256)
void ln2p_kernel(const float* __restrict__ x0, const float* __restrict__ g0,
                 const float* __restrict__ b0, __bf16* __restrict__ y0,
                 const float* __restrict__ x1, const float* __restrict__ g1,
                 const float* __restrict__ b1, __bf16* __restrict__ y1,
                 PrepJobs jobs) {
    __shared__ float tile[64][65];
    __shared__ float red[8];
    int bx = blockIdx.x;
    int t = threadIdx.x;

    if (bx >= 2 * ROWS) {
        // ---- weight-prep path ----
        int tid = bx - 2 * ROWS;
        PrepJob job = jobs.j[tid / 144];
        int rem = tid % 144;
        int k0 = (rem % 12) * 64, n0 = (rem / 12) * 64;
        if (k0 >= job.K || n0 >= job.Npad) return;
        int c = t & 63, r0 = t >> 6;
        #pragma unroll
        for (int i = 0; i < 16; ++i) {
            int kk = i * 4 + r0;
            float v = 0.f;
            if (k0 + kk < job.K && n0 + c < job.N) v = job.W[(size_t)(k0 + kk) * job.N + n0 + c];
            tile[kk][c] = v;
        }
        __syncthreads();
        #pragma unroll
        for (int i = 0; i < 16; ++i) {
            int nn = i * 4 + r0;
            if (n0 + nn < job.Npad && k0 + c < job.K)
                job.Wt[(size_t)(n0 + nn) * job.K + k0 + c] = (__bf16)tile[c][nn];
        }
        return;
    }

    // ---- LayerNorm path ----
    int sel = bx >= ROWS;
    int row = bx - sel * ROWS;
    const float* x = sel ? x1 : x0;
    const float* g = sel ? g1 : g0;
    const float* b = sel ? b1 : b0;
    __bf16* y = sel ? y1 : y0;
    const float* xr = x + (size_t)row * CC;
    __bf16* yr = y + (size_t)row * CC;
    f32x4 xv = {0.f, 0.f, 0.f, 0.f};
    if (t < 192) xv = *(const f32x4*)(xr + t * 4);
    float s  = xv[0] + xv[1] + xv[2] + xv[3];
    float s2 = xv[0]*xv[0] + xv[1]*xv[1] + xv[2]*xv[2] + xv[3]*xv[3];
    float ws = wave_sum64(s), ws2 = wave_sum64(s2);
    int w = t >> 6;
    if ((t & 63) == 0) { red[w] = ws; red[4 + w] = ws2; }
    __syncthreads();
    float S  = red[0] + red[1] + red[2] + red[3];
    float S2 = red[4] + red[5] + red[6] + red[7];
    float mean = S / CC;
    float inv  = rsqrtf(S2 / CC - mean * mean + EPS_);
    if (t < 192) {
        f32x4 gv = *(const f32x4*)(g + t * 4);
        f32x4 bv = *(const f32x4*)(b + t * 4);
        bf16x4 o;
        #pragma unroll
        for (int e = 0; e < 4; ++e)
            o[e] = (__bf16)((xv[e] - mean) * inv * gv[e] + bv[e]);
        *(bf16x4*)(yr + t * 4) = o;
    }
}

// ---------------------------------------------------------------------------
// LayerNorm, bf16 in -> bf16 out, bf16x8 vectorized (96 active threads of 256)
// ---------------------------------------------------------------------------
__global__ __launch_bounds__(256)
void ln_bf_kernel(const __bf16* __restrict__ x, const float* __restrict__ g,
                  const float* __restrict__ b, __bf16* __restrict__ y) {
    int row = blockIdx.x;
    const __bf16* xr = x + (size_t)row * CC;
    __bf16* yr = y + (size_t)row * CC;
    int t = threadIdx.x;
    float xv[8]; bf16x8 raw = {};
    if (t < 96) raw = *(const bf16x8*)(xr + t * 8);
    float s = 0.f, s2 = 0.f;
    #pragma unroll
    for (int e = 0; e < 8; ++e) { xv[e] = (float)raw[e]; s += xv[e]; s2 += xv[e]*xv[e]; }
    __shared__ float red[8];
    float ws = wave_sum64(s), ws2 = wave_sum64(s2);
    int w = t >> 6;
    if ((t & 63) == 0) { red[w] = ws; red[4 + w] = ws2; }
    __syncthreads();
    float S  = red[0] + red[1] + red[2] + red[3];
    float S2 = red[4] + red[5] + red[6] + red[7];
    float mean = S / CC;
    float inv  = rsqrtf(S2 / CC - mean * mean + EPS_);
    if (t < 96) {
        bf16x8 o;
        #pragma unroll
        for (int e = 0; e < 8; ++e)
            o[e] = (__bf16)((xv[e] - mean) * inv * g[t * 8 + e] + b[t * 8 + e]);
        *(bf16x8*)(yr + t * 8) = o;
    }
}

// ---------------------------------------------------------------------------
// Grouped 64x64-tile bf16 MFMA GEMM (round-3 verified body).
// Up to 2 independent jobs per launch, selected by block range; per-job
// bijective XCD swizzle (job nblk always %8==0). 2-buffer LDS (16 KB),
// counted vmcnt, raw s_barrier, 8 blocks/CU.
// flags: 1 gelu, 2 out bf16, 4 res bf16 (res f32 otherwise; res may be null)
// ---------------------------------------------------------------------------
struct G64Job {
    const __bf16* A; const __bf16* Bt;
    const float* ba; const float* bb;
    const void* res; void* out;
    int Nsplit, K, N, flags, nblk, gx;
};

__global__ __launch_bounds__(256, 8)
void gemm64g(G64Job j0, G64Job j1) {
    __shared__ __bf16 As[2][64 * 32];
    __shared__ __bf16 Bs[2][64 * 32];

    int bid = blockIdx.x;
    G64Job jb = j0;
    if (bid >= j0.nblk) { jb = j1; bid -= j0.nblk; }

    int t = threadIdx.x;
    int lane = t & 63, wave = t >> 6;

    // per-job XCD swizzle (nblk %8 == 0 -> bijective)
    int swz = (bid & 7) * (jb.nblk >> 3) + (bid >> 3);
    int bx = swz % jb.gx, by = swz / jb.gx;
    int bm = by * 64, bn = bx * 64;
    int K = jb.K, N = jb.N;

    f32x4 acc[4] = {};

    int row0 = t >> 2, kc0 = (t & 3) ^ ((row0 >> 1) & 3);
    const __bf16* a0 = jb.A  + (size_t)(bm + row0) * K + kc0 * 8;
    const __bf16* b0 = jb.Bt + (size_t)(bn + row0) * K + kc0 * 8;

    int rbase = wave * 16 + (lane & 15);
    int nbase = lane & 15;
    int kq = lane >> 4;

    #define STAGE(bi, kt) do {                                                                   \
        int koff_ = (kt) * 32;                                                                   \
        __builtin_amdgcn_global_load_lds((gbl_vp)(a0 + koff_), (lds_vp)&As[bi][t * 8], 16, 0, 0); \
        __builtin_amdgcn_global_load_lds((gbl_vp)(b0 + koff_), (lds_vp)&Bs[bi][t * 8], 16, 0, 0); \
    } while (0)

    #define COMPUTE(bi) do {                                                                     \
        bf16x8 afr = *(const bf16x8*)&As[bi][rbase * 32 + ((kq ^ ((rbase >> 1) & 3)) * 8)];      \
        _Pragma("unroll")                                                                        \
        for (int j = 0; j < 4; ++j) {                                                            \
            int n = nbase + j * 16;                                                              \
            bf16x8 bfr = *(const bf16x8*)&Bs[bi][n * 32 + ((kq ^ ((n >> 1) & 3)) * 8)];          \
            acc[j] = __builtin_amdgcn_mfma_f32_16x16x32_bf16(afr, bfr, acc[j], 0, 0, 0);         \
        }                                                                                        \
    } while (0)

    int nt = K >> 5;
    STAGE(0, 0);
    STAGE(1, 1);
    for (int tt = 0; tt < nt; ++tt) {
        int cur = tt & 1;
        // wait tile tt's 2 loads; tile tt+1's 2 stay in flight across barrier
        if (tt < nt - 1) asm volatile("s_waitcnt vmcnt(2)\n\ts_barrier" ::: "memory");
        else             asm volatile("s_waitcnt vmcnt(0)\n\ts_barrier" ::: "memory");
        COMPUTE(cur);
        // all waves done reading buf cur before restaging it
        asm volatile("s_waitcnt lgkmcnt(0)\n\ts_barrier" ::: "memory");
        if (tt + 2 < nt) STAGE(cur, tt + 2);
    }

    #undef STAGE
    #undef COMPUTE

    int rowq = lane >> 4;
    int do_gelu = jb.flags & 1, out_bf = jb.flags & 2, res_bf = jb.flags & 4;
    const void* res = jb.res;
    #pragma unroll
    for (int j = 0; j < 4; ++j) {
        int c = bn + j * 16 + (lane & 15);
        if (c < N) {
            float bias = (c < jb.Nsplit) ? jb.ba[c] : jb.bb[c - jb.Nsplit];
            #pragma unroll
            for (int r = 0; r < 4; ++r) {
                int m = bm + wave * 16 + rowq * 4 + r;
                float v = acc[j][r] + bias;
                if (do_gelu) v = 0.5f * v * (1.f + erff(v * 0.70710678118f));
                size_t oi = (size_t)m * N + c;
                if (res) v += res_bf ? (float)((const __bf16*)res)[oi]
                                     : ((const float*)res)[oi];
                if (out_bf) ((__bf16*)jb.out)[oi] = (__bf16)v;
                else        ((float*)jb.out)[oi]  = v;
            }
        }
    }
}

// ---------------------------------------------------------------------------
// Deformable sampling v3: one wave per (b,q,h).
//   lane = p*16 + g : p = sample point (0..3), g = channel group (4 bf16).
// ---------------------------------------------------------------------------
__global__ __launch_bounds__(256)
void sample_kernel(const __bf16* __restrict__ value, const float* __restrict__ offatt,
                   const float* __restrict__ refp, __bf16* __restrict__ out) {
    int wid  = blockIdx.x * 4 + (threadIdx.x >> 6);
    int lane = threadIdx.x & 63;
    int h  = wid % NH_;
    int bq = wid / NH_;
    int b  = bq / LQ;

    const float* oa = offatt + (size_t)bq * 144;
    float rx = refp[(size_t)bq * 2 + 0] * (float)WW - 0.5f;
    float ry = refp[(size_t)bq * 2 + 1] * (float)HH - 0.5f;

    // softmax over this head's 4 logits (wave-uniform -> s_loads)
    float l0 = oa[96 + h * 4 + 0], l1 = oa[96 + h * 4 + 1];
    float l2 = oa[96 + h * 4 + 2], l3 = oa[96 + h * 4 + 3];
    float mx = fmaxf(fmaxf(l0, l1), fmaxf(l2, l3));
    float e0 = __expf(l0 - mx), e1 = __expf(l1 - mx);
    float e2 = __expf(l2 - mx), e3 = __expf(l3 - mx);
    float rs = 1.f / (e0 + e1 + e2 + e3);

    int pp = lane >> 4;       // point id
    int g  = lane & 15;       // channel group
    float wpl = (pp == 0) ? e0 : (pp == 1) ? e1 : (pp == 2) ? e2 : e3;
    wpl *= rs;

    const float* oxy = oa + h * 8 + pp * 2;
    float x = rx + oxy[0];
    float y = ry + oxy[1];
    float x0f = floorf(x), y0f = floorf(y);
    float wx1 = x - x0f, wy1 = y - y0f;
    float wx0 = 1.f - wx1, wy0 = 1.f - wy1;
    int x0 = (int)x0f, y0 = (int)y0f;
    int x1 = x0 + 1, y1 = y0 + 1;
    float mx0 = ((unsigned)x0 < (unsigned)WW) ? wx0 : 0.f;
    float mx1 = ((unsigned)x1 < (unsigned)WW) ? wx1 : 0.f;
    float my0 = (((unsigned)y0 < (unsigned)HH) ? wy0 : 0.f) * wpl;
    float my1 = (((unsigned)y1 < (unsigned)HH) ? wy1 : 0.f) * wpl;
    int xc0 = x0 & (WW - 1), xc1 = x1 & (WW - 1);
    int r0 = (y0 & (HH - 1)) << 6, r1 = (y1 & (HH - 1)) << 6;

    const __bf16* vbase = value + (size_t)b * (LQ * CC) + h * DH + g * 4;
    bf16x4 v00 = *(const bf16x4*)(vbase + (size_t)(r0 + xc0) * CC);
    bf16x4 v01 = *(const bf16x4*)(vbase + (size_t)(r0 + xc1) * CC);
    bf16x4 v10 = *(const bf16x4*)(vbase + (size_t)(r1 + xc0) * CC);
    bf16x4 v11 = *(const bf16x4*)(vbase + (size_t)(r1 + xc1) * CC);
    float w00 = mx0 * my0, w01 = mx1 * my0, w10 = mx0 * my1, w11 = mx1 * my1;

    f32x4 acc;
    #pragma unroll
    for (int e = 0; e < 4; ++e)
        acc[e] = w00 * (float)v00[e] + w01 * (float)v01[e]
               + w10 * (float)v10[e] + w11 * (float)v11[e];

    #pragma unroll
    for (int e = 0; e < 4; ++e) {
        acc[e] += __shfl_xor(acc[e], 16, 64);
        acc[e] += __shfl_xor(acc[e], 32, 64);
    }
    if (pp == 0) {
        bf16x4 o;
        o[0] = (__bf16)acc[0]; o[1] = (__bf16)acc[1];
        o[2] = (__bf16)acc[2]; o[3] = (__bf16)acc[3];
        *(bf16x4*)(out + (size_t)bq * CC + h * DH + g * 4) = o;
    }
}

// ---------------------------------------------------------------------------
// Launch
// ---------------------------------------------------------------------------
extern "C" void kernel_launch(void* const* d_in, const int* in_sizes, int n_in,
                              void* d_out, int out_size, void* d_ws, size_t ws_size,
                              hipStream_t stream) {
    const float* query = (const float*)d_in[0];
    const float* refp  = (const float*)d_in[1];
    const float* feat  = (const float*)d_in[2];
    const float* qn_g  = (const float*)d_in[7];
    const float* qn_b  = (const float*)d_in[8];
    const float* fn_g  = (const float*)d_in[9];
    const float* fn_b  = (const float*)d_in[10];
    const float* Wv    = (const float*)d_in[11];
    const float* bv    = (const float*)d_in[12];
    const float* Woff  = (const float*)d_in[13];
    const float* boff  = (const float*)d_in[14];
    const float* Watt  = (const float*)d_in[15];
    const float* batt  = (const float*)d_in[16];
    const float* Wout  = (const float*)d_in[17];
    const float* bout  = (const float*)d_in[18];
    const float* ffn_g = (const float*)d_in[19];
    const float* ffn_b = (const float*)d_in[20];
    const float* W1    = (const float*)d_in[21];
    const float* b1    = (const float*)d_in[22];
    const float* W2    = (const float*)d_in[23];
    const float* b2    = (const float*)d_in[24];
    float* out = (float*)d_out;

    // workspace layout (byte offsets)
    char* ws = (char*)d_ws;
    __bf16* WvT    = (__bf16*)(ws + 0);            // 1179648
    __bf16* WcombT = (__bf16*)(ws + 1179648);      // 192x768x2 = 294912 (slot 393216)
    __bf16* WoutT  = (__bf16*)(ws + 1572864);      // 1179648
    __bf16* W1T    = (__bf16*)(ws + 2752512);      // 192x768x2 = 294912 (slot 393216)
    __bf16* W2T    = (__bf16*)(ws + 3145728);      // 294912
    float*  offatt_f = (float*)(ws + 3670016);     // 9437184
    __bf16* h1_bf    = (__bf16*)offatt_f;          // reuse
    __bf16* bufA     = (__bf16*)(ws + 13107200);   // 25165824
    __bf16* qn_bf    = bufA;
    __bf16* value_bf = bufA;
    __bf16* bufB     = (__bf16*)(ws + 38273024);   // 25165824
    __bf16* fn_bf    = bufB;
    __bf16* samp_bf  = bufB;
    __bf16* h_bf     = bufB;
    __bf16* attn_bf  = (__bf16*)(ws + 63438848);   // 25165824

    dim3 blk(256);

    // 0+1. merged: both input LayerNorms + batched weight prep (one launch)
    PrepJobs jobs;
    jobs.j[0] = {Wv,   WvT,             768, 768, 768};
    jobs.j[1] = {Woff, WcombT,          768,  96,  96};
    jobs.j[2] = {Watt, WcombT + 96*768, 768,  48,  96};  // comb rows 96..191 (144..191 zero)
    jobs.j[3] = {Wout, WoutT,           768, 768, 768};
    jobs.j[4] = {W1,   W1T,             768, 192, 192};
    jobs.j[5] = {W2,   W2T,             192, 768, 768};
    ln2p_kernel<<<2 * ROWS + 864, blk, 0, stream>>>(query, qn_g, qn_b, qn_bf,
                                                    feat,  fn_g, fn_b, fn_bf, jobs);

    // 2+3. grouped: offatt = qn @ [Woff|Watt]  AND  value = fn @ Wv + bv
    G64Job joff = {qn_bf, WcombT, boff, batt, nullptr, offatt_f,
                   96, CC, 144, 0, 768, 3};
    G64Job jval = {fn_bf, WvT, bv, bv, nullptr, value_bf,
                   CC, CC, CC, 2, 3072, 12};
    gemm64g<<<768 + 3072, blk, 0, stream>>>(joff, jval);

    // 4. deformable sampling -> bf16
    sample_kernel<<<ROWS * NH_ / 4, blk, 0, stream>>>(value_bf, offatt_f, refp, samp_bf);

    // 5. attnres = query + samp @ Wout + bout (bf16 out, f32 res)
    G64Job jout = {samp_bf, WoutT, bout, bout, query, attn_bf,
                   CC, CC, CC, 2, 3072, 12};
    gemm64g<<<3072, blk, 0, stream>>>(jout, jout);

    // 6. h = LN(attnres) -> bf16
    ln_bf_kernel<<<ROWS, blk, 0, stream>>>(attn_bf, ffn_g, ffn_b, h_bf);

    // 7. h1 = gelu(h @ W1 + b1) -> bf16 (N=192)
    G64Job jw1 = {h_bf, W1T, b1, b1, nullptr, h1_bf,
                  HID, CC, HID, 1 | 2, 768, 3};
    gemm64g<<<768, blk, 0, stream>>>(jw1, jw1);

    // 8. out = attnres + h1 @ W2 + b2 (K=192, f32 out, bf16 res)
    G64Job jw2 = {h1_bf, W2T, b2, b2, attn_bf, out,
                  CC, HID, CC, 4, 3072, 12};
    gemm64g<<<3072, blk, 0, stream>>>(jw2, jw2);
}

// Round 7
// 408.458 us; speedup vs baseline: 1.8039x; 1.0458x over previous
//
#include <hip/hip_runtime.h>
#include <hip/hip_bf16.h>
#include <math.h>

// Problem constants:
//   B=4, Lq=4096, C=768, NH=12, d=64, NP=4, nl=1, H=W=64, Lin=4096, hid=192
#define B_    4
#define LQ    4096
#define CC    768
#define NH_   12
#define DH    64
#define NP_   4
#define HH    64
#define WW    64
#define HID   192
#define ROWS  (B_ * LQ)          // 16384
#define EPS_  1e-5f

typedef __bf16 bf16x8 __attribute__((ext_vector_type(8)));
typedef __bf16 bf16x4 __attribute__((ext_vector_type(4)));
typedef float  f32x4  __attribute__((ext_vector_type(4)));

typedef __attribute__((address_space(3))) void* lds_vp;
typedef const __attribute__((address_space(1))) void* gbl_vp;

// fp8 e4m3 (OCP on gfx950) conversion via v_cvt_pk_fp8_f32 (RNE, saturating)
__device__ __forceinline__ unsigned pk4_f8(float a, float b, float c, float d) {
    unsigned lo, hi;
    asm volatile("v_cvt_pk_fp8_f32 %0, %1, %2" : "=v"(lo) : "v"(a), "v"(b));
    asm volatile("v_cvt_pk_fp8_f32 %0, %1, %2" : "=v"(hi) : "v"(c), "v"(d));
    return (lo & 0xffffu) | (hi << 16);
}
__device__ __forceinline__ unsigned char to_f8(float a) {
    unsigned r;
    asm volatile("v_cvt_pk_fp8_f32 %0, %1, %1" : "=v"(r) : "v"(a));
    return (unsigned char)r;
}

// ---------------------------------------------------------------------------
// Weight prep: f32 [K,N] -> fp8 e4m3 [Npad][K] transposed, values x64.
// (weights ~N(0,0.02) sit below e4m3 normal range; x64 -> ~N(0,1.28))
// ---------------------------------------------------------------------------
struct PrepJob { const float* W; unsigned char* Wt; int K; int N; int Npad; };
struct PrepJobs { PrepJob j[6]; };

// ---------------------------------------------------------------------------
// Reductions
// ---------------------------------------------------------------------------
__inline__ __device__ float wave_sum64(float v) {
    #pragma unroll
    for (int o = 32; o > 0; o >>= 1) v += __shfl_down(v, o, 64);
    return v;
}

// ---------------------------------------------------------------------------
// Merged launch: dual LayerNorm (f32 in, fp8 out) + fp8 weight prep.
// blocks [0, 2*ROWS): LN rows; blocks [2*ROWS, +864): prep tiles.
// ---------------------------------------------------------------------------
__global__ __launch_bounds__(256)
void ln2p_kernel(const float* __restrict__ x0, const float* __restrict__ g0,
                 const float* __restrict__ b0, unsigned char* __restrict__ y0,
                 const float* __restrict__ x1, const float* __restrict__ g1,
                 const float* __restrict__ b1, unsigned char* __restrict__ y1,
                 PrepJobs jobs) {
    __shared__ float tile[64][65];
    __shared__ float red[8];
    int bx = blockIdx.x;
    int t = threadIdx.x;

    if (bx >= 2 * ROWS) {
        // ---- weight-prep path (fp8 x64) ----
        int tid = bx - 2 * ROWS;
        PrepJob job = jobs.j[tid / 144];
        int rem = tid % 144;
        int k0 = (rem % 12) * 64, n0 = (rem / 12) * 64;
        if (k0 >= job.K || n0 >= job.Npad) return;
        int c = t & 63, r0 = t >> 6;
        #pragma unroll
        for (int i = 0; i < 16; ++i) {
            int kk = i * 4 + r0;
            float v = 0.f;
            if (k0 + kk < job.K && n0 + c < job.N) v = job.W[(size_t)(k0 + kk) * job.N + n0 + c];
            tile[kk][c] = v;
        }
        __syncthreads();
        #pragma unroll
        for (int i = 0; i < 16; ++i) {
            int nn = i * 4 + r0;
            if (n0 + nn < job.Npad && k0 + c < job.K)
                job.Wt[(size_t)(n0 + nn) * job.K + k0 + c] = to_f8(tile[c][nn] * 64.f);
        }
        return;
    }

    // ---- LayerNorm path ----
    int sel = bx >= ROWS;
    int row = bx - sel * ROWS;
    const float* x = sel ? x1 : x0;
    const float* g = sel ? g1 : g0;
    const float* b = sel ? b1 : b0;
    unsigned char* y = sel ? y1 : y0;
    const float* xr = x + (size_t)row * CC;
    unsigned char* yr = y + (size_t)row * CC;
    f32x4 xv = {0.f, 0.f, 0.f, 0.f};
    if (t < 192) xv = *(const f32x4*)(xr + t * 4);
    float s  = xv[0] + xv[1] + xv[2] + xv[3];
    float s2 = xv[0]*xv[0] + xv[1]*xv[1] + xv[2]*xv[2] + xv[3]*xv[3];
    float ws = wave_sum64(s), ws2 = wave_sum64(s2);
    int w = t >> 6;
    if ((t & 63) == 0) { red[w] = ws; red[4 + w] = ws2; }
    __syncthreads();
    float S  = red[0] + red[1] + red[2] + red[3];
    float S2 = red[4] + red[5] + red[6] + red[7];
    float mean = S / CC;
    float inv  = rsqrtf(S2 / CC - mean * mean + EPS_);
    if (t < 192) {
        f32x4 gv = *(const f32x4*)(g + t * 4);
        f32x4 bv = *(const f32x4*)(b + t * 4);
        float o[4];
        #pragma unroll
        for (int e = 0; e < 4; ++e)
            o[e] = (xv[e] - mean) * inv * gv[e] + bv[e];
        *(unsigned*)(yr + t * 4) = pk4_f8(o[0], o[1], o[2], o[3]);
    }
}

// ---------------------------------------------------------------------------
// LayerNorm, bf16 in -> fp8 out (96 active threads of 256)
// ---------------------------------------------------------------------------
__global__ __launch_bounds__(256)
void ln_bf_kernel(const __bf16* __restrict__ x, const float* __restrict__ g,
                  const float* __restrict__ b, unsigned char* __restrict__ y) {
    int row = blockIdx.x;
    const __bf16* xr = x + (size_t)row * CC;
    unsigned char* yr = y + (size_t)row * CC;
    int t = threadIdx.x;
    float xv[8]; bf16x8 raw = {};
    if (t < 96) raw = *(const bf16x8*)(xr + t * 8);
    float s = 0.f, s2 = 0.f;
    #pragma unroll
    for (int e = 0; e < 8; ++e) { xv[e] = (float)raw[e]; s += xv[e]; s2 += xv[e]*xv[e]; }
    __shared__ float red[8];
    float ws = wave_sum64(s), ws2 = wave_sum64(s2);
    int w = t >> 6;
    if ((t & 63) == 0) { red[w] = ws; red[4 + w] = ws2; }
    __syncthreads();
    float S  = red[0] + red[1] + red[2] + red[3];
    float S2 = red[4] + red[5] + red[6] + red[7];
    float mean = S / CC;
    float inv  = rsqrtf(S2 / CC - mean * mean + EPS_);
    if (t < 96) {
        float o[8];
        #pragma unroll
        for (int e = 0; e < 8; ++e)
            o[e] = (xv[e] - mean) * inv * g[t * 8 + e] + b[t * 8 + e];
        uint2 pk;
        pk.x = pk4_f8(o[0], o[1], o[2], o[3]);
        pk.y = pk4_f8(o[4], o[5], o[6], o[7]);
        *(uint2*)(yr + t * 8) = pk;
    }
}

// ---------------------------------------------------------------------------
// Grouped 64x64-tile FP8 MFMA GEMM. A fp8 [M][K], B fp8 [Npad][K] (x64).
// 3-deep LDS pipeline (12 KB total), counted vmcnt (1 load/wave/step),
// raw s_barrier, per-job bijective XCD swizzle, 8 blocks/CU.
// Staging: waves 0-1 -> A rows, waves 2-3 -> B rows; linear LDS dest +
// inverse-swizzled global source (chunk-XOR by (r>>2)&1, 16B-pair safe).
// flags: 1 gelu, 2 out bf16, 4 res bf16, 8 out fp8 (else f32 out)
// ---------------------------------------------------------------------------
struct G64Job {
    const unsigned char* A; const unsigned char* Bt;
    const float* ba; const float* bb;
    const void* res; void* out;
    int Nsplit, K, N, flags, nblk, gx;
};

__global__ __launch_bounds__(256, 8)
void gemm64f8(G64Job j0, G64Job j1) {
    __shared__ unsigned char As[3][2048];
    __shared__ unsigned char Bs[3][2048];

    int bid = blockIdx.x;
    G64Job jb = j0;
    if (bid >= j0.nblk) { jb = j1; bid -= j0.nblk; }

    int t = threadIdx.x;
    int lane = t & 63, wave = t >> 6;

    int swz = (bid & 7) * (jb.nblk >> 3) + (bid >> 3);
    int bx = swz % jb.gx, by = swz / jb.gx;
    int bm = by * 64, bn = bx * 64;
    int K = jb.K, N = jb.N;

    f32x4 acc[4] = {};

    // staging source (per thread): half-warp-pair covers 64 rows x 32B
    int local = t & 127;
    int r = local >> 1, hch = local & 1;
    int sw = (r >> 2) & 1;
    const unsigned char* sbase = (wave < 2)
        ? jb.A  + (size_t)(bm + r) * K + ((hch ^ sw) << 4)
        : jb.Bt + (size_t)(bn + r) * K + ((hch ^ sw) << 4);

    // compute-side swizzled read offsets
    int rsel = lane & 15, kq = lane >> 4;
    int ra = wave * 16 + rsel;
    int aoff = ra * 32 + ((((kq >> 1) ^ ((ra >> 2) & 1)) << 4) | ((kq & 1) << 3));
    int boffs[4];
    #pragma unroll
    for (int j = 0; j < 4; ++j) {
        int n = rsel + j * 16;
        boffs[j] = n * 32 + ((((kq >> 1) ^ ((n >> 2) & 1)) << 4) | ((kq & 1) << 3));
    }

    #define STAGE(bi, kt) do {                                                                    \
        if (wave < 2)                                                                             \
            __builtin_amdgcn_global_load_lds((gbl_vp)(sbase + (kt) * 32),                         \
                (lds_vp)&As[bi][t * 16], 16, 0, 0);                                               \
        else                                                                                      \
            __builtin_amdgcn_global_load_lds((gbl_vp)(sbase + (kt) * 32),                         \
                (lds_vp)&Bs[bi][(t - 128) * 16], 16, 0, 0);                                       \
    } while (0)

    #define COMPUTE(bi) do {                                                                      \
        long afr = *(const long*)&As[bi][aoff];                                                   \
        _Pragma("unroll")                                                                         \
        for (int j = 0; j < 4; ++j) {                                                             \
            long bfr = *(const long*)&Bs[bi][boffs[j]];                                           \
            acc[j] = __builtin_amdgcn_mfma_f32_16x16x32_fp8_fp8(afr, bfr, acc[j], 0, 0, 0);       \
        }                                                                                         \
    } while (0)

    int nt = K >> 5;                 // 24 (K=768) or 6 (K=192); always >= 3
    STAGE(0, 0);
    STAGE(1, 1);
    STAGE(2, 2);
    int bi = 0;
    for (int tt = 0; tt < nt; ++tt) {
        if (tt < nt - 2)       asm volatile("s_waitcnt vmcnt(2)\n\ts_barrier" ::: "memory");
        else if (tt == nt - 2) asm volatile("s_waitcnt vmcnt(1)\n\ts_barrier" ::: "memory");
        else                   asm volatile("s_waitcnt vmcnt(0)\n\ts_barrier" ::: "memory");
        COMPUTE(bi);
        asm volatile("s_waitcnt lgkmcnt(0)\n\ts_barrier" ::: "memory");
        if (tt + 3 < nt) STAGE(bi, tt + 3);
        ++bi; if (bi == 3) bi = 0;
    }

    #undef STAGE
    #undef COMPUTE

    int rowq = lane >> 4;
    int do_gelu = jb.flags & 1, out_bf = jb.flags & 2, res_bf = jb.flags & 4, out_f8 = jb.flags & 8;
    const void* res = jb.res;
    #pragma unroll
    for (int j = 0; j < 4; ++j) {
        int c = bn + j * 16 + rsel;
        if (c < N) {
            float bias = (c < jb.Nsplit) ? jb.ba[c] : jb.bb[c - jb.Nsplit];
            #pragma unroll
            for (int r4 = 0; r4 < 4; ++r4) {
                int m = bm + wave * 16 + rowq * 4 + r4;
                float v = acc[j][r4] * 0.015625f + bias;   // descale weights x64
                if (do_gelu) v = 0.5f * v * (1.f + erff(v * 0.70710678118f));
                size_t oi = (size_t)m * N + c;
                if (res) v += res_bf ? (float)((const __bf16*)res)[oi]
                                     : ((const float*)res)[oi];
                if (out_f8)      ((unsigned char*)jb.out)[oi] = to_f8(v);
                else if (out_bf) ((__bf16*)jb.out)[oi] = (__bf16)v;
                else             ((float*)jb.out)[oi]  = v;
            }
        }
    }
}

// ---------------------------------------------------------------------------
// Deformable sampling: one wave per (b,q,h); value bf16 in, fp8 out.
// ---------------------------------------------------------------------------
__global__ __launch_bounds__(256)
void sample_kernel(const __bf16* __restrict__ value, const float* __restrict__ offatt,
                   const float* __restrict__ refp, unsigned char* __restrict__ out) {
    int wid  = blockIdx.x * 4 + (threadIdx.x >> 6);
    int lane = threadIdx.x & 63;
    int h  = wid % NH_;
    int bq = wid / NH_;
    int b  = bq / LQ;

    const float* oa = offatt + (size_t)bq * 144;
    float rx = refp[(size_t)bq * 2 + 0] * (float)WW - 0.5f;
    float ry = refp[(size_t)bq * 2 + 1] * (float)HH - 0.5f;

    float l0 = oa[96 + h * 4 + 0], l1 = oa[96 + h * 4 + 1];
    float l2 = oa[96 + h * 4 + 2], l3 = oa[96 + h * 4 + 3];
    float mx = fmaxf(fmaxf(l0, l1), fmaxf(l2, l3));
    float e0 = __expf(l0 - mx), e1 = __expf(l1 - mx);
    float e2 = __expf(l2 - mx), e3 = __expf(l3 - mx);
    float rs = 1.f / (e0 + e1 + e2 + e3);

    int pp = lane >> 4;       // point id
    int g  = lane & 15;       // channel group
    float wpl = (pp == 0) ? e0 : (pp == 1) ? e1 : (pp == 2) ? e2 : e3;
    wpl *= rs;

    const float* oxy = oa + h * 8 + pp * 2;
    float x = rx + oxy[0];
    float y = ry + oxy[1];
    float x0f = floorf(x), y0f = floorf(y);
    float wx1 = x - x0f, wy1 = y - y0f;
    float wx0 = 1.f - wx1, wy0 = 1.f - wy1;
    int x0 = (int)x0f, y0 = (int)y0f;
    int x1 = x0 + 1, y1 = y0 + 1;
    float mx0 = ((unsigned)x0 < (unsigned)WW) ? wx0 : 0.f;
    float mx1 = ((unsigned)x1 < (unsigned)WW) ? wx1 : 0.f;
    float my0 = (((unsigned)y0 < (unsigned)HH) ? wy0 : 0.f) * wpl;
    float my1 = (((unsigned)y1 < (unsigned)HH) ? wy1 : 0.f) * wpl;
    int xc0 = x0 & (WW - 1), xc1 = x1 & (WW - 1);
    int r0 = (y0 & (HH - 1)) << 6, r1 = (y1 & (HH - 1)) << 6;

    const __bf16* vbase = value + (size_t)b * (LQ * CC) + h * DH + g * 4;
    bf16x4 v00 = *(const bf16x4*)(vbase + (size_t)(r0 + xc0) * CC);
    bf16x4 v01 = *(const bf16x4*)(vbase + (size_t)(r0 + xc1) * CC);
    bf16x4 v10 = *(const bf16x4*)(vbase + (size_t)(r1 + xc0) * CC);
    bf16x4 v11 = *(const bf16x4*)(vbase + (size_t)(r1 + xc1) * CC);
    float w00 = mx0 * my0, w01 = mx1 * my0, w10 = mx0 * my1, w11 = mx1 * my1;

    f32x4 acc;
    #pragma unroll
    for (int e = 0; e < 4; ++e)
        acc[e] = w00 * (float)v00[e] + w01 * (float)v01[e]
               + w10 * (float)v10[e] + w11 * (float)v11[e];

    #pragma unroll
    for (int e = 0; e < 4; ++e) {
        acc[e] += __shfl_xor(acc[e], 16, 64);
        acc[e] += __shfl_xor(acc[e], 32, 64);
    }
    if (pp == 0) {
        *(unsigned*)(out + (size_t)bq * CC + h * DH + g * 4) =
            pk4_f8(acc[0], acc[1], acc[2], acc[3]);
    }
}

// ---------------------------------------------------------------------------
// Launch
// ---------------------------------------------------------------------------
extern "C" void kernel_launch(void* const* d_in, const int* in_sizes, int n_in,
                              void* d_out, int out_size, void* d_ws, size_t ws_size,
                              hipStream_t stream) {
    const float* query = (const float*)d_in[0];
    const float* refp  = (const float*)d_in[1];
    const float* feat  = (const float*)d_in[2];
    const float* qn_g  = (const float*)d_in[7];
    const float* qn_b  = (const float*)d_in[8];
    const float* fn_g  = (const float*)d_in[9];
    const float* fn_b  = (const float*)d_in[10];
    const float* Wv    = (const float*)d_in[11];
    const float* bv    = (const float*)d_in[12];
    const float* Woff  = (const float*)d_in[13];
    const float* boff  = (const float*)d_in[14];
    const float* Watt  = (const float*)d_in[15];
    const float* batt  = (const float*)d_in[16];
    const float* Wout  = (const float*)d_in[17];
    const float* bout  = (const float*)d_in[18];
    const float* ffn_g = (const float*)d_in[19];
    const float* ffn_b = (const float*)d_in[20];
    const float* W1    = (const float*)d_in[21];
    const float* b1    = (const float*)d_in[22];
    const float* W2    = (const float*)d_in[23];
    const float* b2    = (const float*)d_in[24];
    float* out = (float*)d_out;

    // workspace layout (byte offsets, all within the proven 88.6 MB footprint)
    char* ws = (char*)d_ws;
    unsigned char* Wv8    = (unsigned char*)(ws + 0);        // 589824
    unsigned char* Wcomb8 = (unsigned char*)(ws + 1179648);  // 147456 (192x768)
    unsigned char* Wout8  = (unsigned char*)(ws + 1572864);  // 589824
    unsigned char* W18    = (unsigned char*)(ws + 2752512);  // 147456
    unsigned char* W28    = (unsigned char*)(ws + 3145728);  // 147456
    float*  offatt_f = (float*)(ws + 3670016);               // 9437184
    unsigned char* h1_f8 = (unsigned char*)offatt_f;         // 3.1MB, reuse (offatt dead after sample)
    __bf16* value_bf = (__bf16*)(ws + 13107200);             // 25165824
    unsigned char* fn_f8   = (unsigned char*)(ws + 38273024); // 12.6MB
    unsigned char* samp_f8 = fn_f8;                           // reuse (fn dead after value GEMM)
    unsigned char* qn_f8   = (unsigned char*)(ws + 50855936); // 12.6MB
    unsigned char* h_f8    = qn_f8;                           // reuse (qn dead after offatt GEMM)
    __bf16* attn_bf  = (__bf16*)(ws + 63438848);             // 25165824

    dim3 blk(256);

    // 0+1. merged: both input LayerNorms (fp8 out) + fp8 weight prep
    PrepJobs jobs;
    jobs.j[0] = {Wv,   Wv8,             768, 768, 768};
    jobs.j[1] = {Woff, Wcomb8,          768,  96,  96};
    jobs.j[2] = {Watt, Wcomb8 + 96*768, 768,  48,  96};  // comb rows 96..191 (144..191 zero)
    jobs.j[3] = {Wout, Wout8,           768, 768, 768};
    jobs.j[4] = {W1,   W18,             768, 192, 192};
    jobs.j[5] = {W2,   W28,             192, 768, 768};
    ln2p_kernel<<<2 * ROWS + 864, blk, 0, stream>>>(query, qn_g, qn_b, qn_f8,
                                                    feat,  fn_g, fn_b, fn_f8, jobs);

    // 2+3. grouped fp8: offatt = qn @ [Woff|Watt]  AND  value = fn @ Wv + bv
    //      (no buffer overlap: off reads qn_f8, val reads fn_f8, writes value_bf)
    G64Job joff = {qn_f8, Wcomb8, boff, batt, nullptr, offatt_f,
                   96, CC, 144, 0, 768, 3};
    G64Job jval = {fn_f8, Wv8, bv, bv, nullptr, value_bf,
                   CC, CC, CC, 2, 3072, 12};
    gemm64f8<<<768 + 3072, blk, 0, stream>>>(joff, jval);

    // 4. deformable sampling -> fp8
    sample_kernel<<<ROWS * NH_ / 4, blk, 0, stream>>>(value_bf, offatt_f, refp, samp_f8);

    // 5. attnres = query + samp @ Wout + bout (bf16 out, f32 res)
    G64Job jout5 = {samp_f8, Wout8, bout, bout, query, attn_bf,
                    CC, CC, CC, 2, 3072, 12};
    gemm64f8<<<3072, blk, 0, stream>>>(jout5, jout5);

    // 6. h = LN(attnres) -> fp8
    ln_bf_kernel<<<ROWS, blk, 0, stream>>>(attn_bf, ffn_g, ffn_b, h_f8);

    // 7. h1 = gelu(h @ W1 + b1) -> fp8 (N=192)
    G64Job jw1 = {h_f8, W18, b1, b1, nullptr, h1_f8,
                  HID, CC, HID, 1 | 8, 768, 3};
    gemm64f8<<<768, blk, 0, stream>>>(jw1, jw1);

    // 8. out = attnres + h1 @ W2 + b2 (K=192, f32 out, bf16 res)
    G64Job jw2 = {h1_f8, W28, b2, b2, attn_bf, out,
                  CC, HID, CC, 4, 3072, 12};
    gemm64f8<<<3072, blk, 0, stream>>>(jw2, jw2);
}

// Round 8
// 374.527 us; speedup vs baseline: 1.9673x; 1.0906x over previous
//
#include <hip/hip_runtime.h>
#include <hip/hip_bf16.h>
#include <math.h>

// Problem constants:
//   B=4, Lq=4096, C=768, NH=12, d=64, NP=4, nl=1, H=W=64, Lin=4096, hid=192
#define B_    4
#define LQ    4096
#define CC    768
#define NH_   12
#define DH    64
#define NP_   4
#define HH    64
#define WW    64
#define HID   192
#define ROWS  (B_ * LQ)          // 16384
#define EPS_  1e-5f

typedef __bf16 bf16x8 __attribute__((ext_vector_type(8)));
typedef __bf16 bf16x4 __attribute__((ext_vector_type(4)));
typedef float  f32x4  __attribute__((ext_vector_type(4)));

typedef __attribute__((address_space(3))) void* lds_vp;
typedef const __attribute__((address_space(1))) void* gbl_vp;

// fp8 e4m3 (OCP on gfx950) conversion via v_cvt_pk_fp8_f32 (RNE, saturating)
__device__ __forceinline__ unsigned pk4_f8(float a, float b, float c, float d) {
    unsigned lo, hi;
    asm volatile("v_cvt_pk_fp8_f32 %0, %1, %2" : "=v"(lo) : "v"(a), "v"(b));
    asm volatile("v_cvt_pk_fp8_f32 %0, %1, %2" : "=v"(hi) : "v"(c), "v"(d));
    return (lo & 0xffffu) | (hi << 16);
}
__device__ __forceinline__ unsigned char to_f8(float a) {
    unsigned r;
    asm volatile("v_cvt_pk_fp8_f32 %0, %1, %1" : "=v"(r) : "v"(a));
    return (unsigned char)r;
}

// ---------------------------------------------------------------------------
// Weight prep: f32 [K,N] -> fp8 e4m3 [Npad][K] transposed, values x64.
// ---------------------------------------------------------------------------
struct PrepJob { const float* W; unsigned char* Wt; int K; int N; int Npad; };
struct PrepJobs { PrepJob j[6]; };

// ---------------------------------------------------------------------------
// Reductions
// ---------------------------------------------------------------------------
__inline__ __device__ float wave_sum64(float v) {
    #pragma unroll
    for (int o = 32; o > 0; o >>= 1) v += __shfl_down(v, o, 64);
    return v;
}

// ---------------------------------------------------------------------------
// Merged launch: dual LayerNorm (f32 in, fp8 out) + fp8 weight prep.
// ---------------------------------------------------------------------------
__global__ __launch_bounds__(256)
void ln2p_kernel(const float* __restrict__ x0, const float* __restrict__ g0,
                 const float* __restrict__ b0, unsigned char* __restrict__ y0,
                 const float* __restrict__ x1, const float* __restrict__ g1,
                 const float* __restrict__ b1, unsigned char* __restrict__ y1,
                 PrepJobs jobs) {
    __shared__ float tile[64][65];
    __shared__ float red[8];
    int bx = blockIdx.x;
    int t = threadIdx.x;

    if (bx >= 2 * ROWS) {
        // ---- weight-prep path (fp8 x64) ----
        int tid = bx - 2 * ROWS;
        PrepJob job = jobs.j[tid / 144];
        int rem = tid % 144;
        int k0 = (rem % 12) * 64, n0 = (rem / 12) * 64;
        if (k0 >= job.K || n0 >= job.Npad) return;
        int c = t & 63, r0 = t >> 6;
        #pragma unroll
        for (int i = 0; i < 16; ++i) {
            int kk = i * 4 + r0;
            float v = 0.f;
            if (k0 + kk < job.K && n0 + c < job.N) v = job.W[(size_t)(k0 + kk) * job.N + n0 + c];
            tile[kk][c] = v;
        }
        __syncthreads();
        #pragma unroll
        for (int i = 0; i < 16; ++i) {
            int nn = i * 4 + r0;
            if (n0 + nn < job.Npad && k0 + c < job.K)
                job.Wt[(size_t)(n0 + nn) * job.K + k0 + c] = to_f8(tile[c][nn] * 64.f);
        }
        return;
    }

    // ---- LayerNorm path ----
    int sel = bx >= ROWS;
    int row = bx - sel * ROWS;
    const float* x = sel ? x1 : x0;
    const float* g = sel ? g1 : g0;
    const float* b = sel ? b1 : b0;
    unsigned char* y = sel ? y1 : y0;
    const float* xr = x + (size_t)row * CC;
    unsigned char* yr = y + (size_t)row * CC;
    f32x4 xv = {0.f, 0.f, 0.f, 0.f};
    if (t < 192) xv = *(const f32x4*)(xr + t * 4);
    float s  = xv[0] + xv[1] + xv[2] + xv[3];
    float s2 = xv[0]*xv[0] + xv[1]*xv[1] + xv[2]*xv[2] + xv[3]*xv[3];
    float ws = wave_sum64(s), ws2 = wave_sum64(s2);
    int w = t >> 6;
    if ((t & 63) == 0) { red[w] = ws; red[4 + w] = ws2; }
    __syncthreads();
    float S  = red[0] + red[1] + red[2] + red[3];
    float S2 = red[4] + red[5] + red[6] + red[7];
    float mean = S / CC;
    float inv  = rsqrtf(S2 / CC - mean * mean + EPS_);
    if (t < 192) {
        f32x4 gv = *(const f32x4*)(g + t * 4);
        f32x4 bv = *(const f32x4*)(b + t * 4);
        float o[4];
        #pragma unroll
        for (int e = 0; e < 4; ++e)
            o[e] = (xv[e] - mean) * inv * gv[e] + bv[e];
        *(unsigned*)(yr + t * 4) = pk4_f8(o[0], o[1], o[2], o[3]);
    }
}

// ---------------------------------------------------------------------------
// LayerNorm, bf16 in -> fp8 out (96 active threads of 256)
// ---------------------------------------------------------------------------
__global__ __launch_bounds__(256)
void ln_bf_kernel(const __bf16* __restrict__ x, const float* __restrict__ g,
                  const float* __restrict__ b, unsigned char* __restrict__ y) {
    int row = blockIdx.x;
    const __bf16* xr = x + (size_t)row * CC;
    unsigned char* yr = y + (size_t)row * CC;
    int t = threadIdx.x;
    float xv[8]; bf16x8 raw = {};
    if (t < 96) raw = *(const bf16x8*)(xr + t * 8);
    float s = 0.f, s2 = 0.f;
    #pragma unroll
    for (int e = 0; e < 8; ++e) { xv[e] = (float)raw[e]; s += xv[e]; s2 += xv[e]*xv[e]; }
    __shared__ float red[8];
    float ws = wave_sum64(s), ws2 = wave_sum64(s2);
    int w = t >> 6;
    if ((t & 63) == 0) { red[w] = ws; red[4 + w] = ws2; }
    __syncthreads();
    float S  = red[0] + red[1] + red[2] + red[3];
    float S2 = red[4] + red[5] + red[6] + red[7];
    float mean = S / CC;
    float inv  = rsqrtf(S2 / CC - mean * mean + EPS_);
    if (t < 96) {
        float o[8];
        #pragma unroll
        for (int e = 0; e < 8; ++e)
            o[e] = (xv[e] - mean) * inv * g[t * 8 + e] + b[t * 8 + e];
        uint2 pk;
        pk.x = pk4_f8(o[0], o[1], o[2], o[3]);
        pk.y = pk4_f8(o[4], o[5], o[6], o[7]);
        *(uint2*)(yr + t * 8) = pk;
    }
}

// ---------------------------------------------------------------------------
// Grouped 64x64-tile FP8 MFMA GEMM, BK=64: 12 K-steps for K=768 (was 24),
// ONE barrier per K-step (3-buffer distance-2 schedule; safety: a wave
// reaches barrier(t+1) only after its MFMAs consumed buf-t ds_reads, so
// staging buf (t-1)%3 after that barrier cannot race readers).
// 24 KB LDS -> 6 blocks/CU. Counted vmcnt (2 loads/thread/step).
// Chunk-XOR swizzle: LDS row 64 B = 4 chunks of 16 B; chunk' = chunk ^
// ((row>>2)&3); global source inverse-swizzled, reads swizzled (<=4-way =
// minimum aliasing for a 512 B b64 wave read).
// flags: 1 gelu, 2 out bf16, 4 res bf16, 8 out fp8 (else f32 out)
// ---------------------------------------------------------------------------
struct G64Job {
    const unsigned char* A; const unsigned char* Bt;
    const float* ba; const float* bb;
    const void* res; void* out;
    int Nsplit, K, N, flags, nblk, gx;
};

__global__ __launch_bounds__(256, 6)
void gemm64f8(G64Job j0, G64Job j1) {
    __shared__ unsigned char As[3][4096];
    __shared__ unsigned char Bs[3][4096];

    int bid = blockIdx.x;
    G64Job jb = j0;
    if (bid >= j0.nblk) { jb = j1; bid -= j0.nblk; }

    int t = threadIdx.x;
    int lane = t & 63, wave = t >> 6;

    int swz = (bid & 7) * (jb.nblk >> 3) + (bid >> 3);
    int bx = swz % jb.gx, by = swz / jb.gx;
    int bm = by * 64, bn = bx * 64;
    int K = jb.K, N = jb.N;

    f32x4 acc[4] = {};

    // staging: thread t covers row r = t>>2 (0..63), LDS chunk cp = t&3;
    // global chunk gc = cp ^ ((r>>2)&3)  (inverse swizzle, linear LDS dest)
    int r = t >> 2, cp = t & 3;
    int gc = cp ^ ((r >> 2) & 3);
    const unsigned char* aS = jb.A  + (size_t)(bm + r) * K + gc * 16;
    const unsigned char* bS = jb.Bt + (size_t)(bn + r) * K + gc * 16;

    // compute-side swizzled read offsets: row ra, k-half h, lane kq
    int rsel = lane & 15, kq = lane >> 4;
    int ra = wave * 16 + rsel;
    int aoff[2], boff[4][2];
    #pragma unroll
    for (int h = 0; h < 2; ++h) {
        int ch = ((h << 1) | (kq >> 1)) ^ ((ra >> 2) & 3);
        aoff[h] = ra * 64 + ch * 16 + (kq & 1) * 8;
        #pragma unroll
        for (int j = 0; j < 4; ++j) {
            int n = rsel + j * 16;
            int cb = ((h << 1) | (kq >> 1)) ^ ((n >> 2) & 3);
            boff[j][h] = n * 64 + cb * 16 + (kq & 1) * 8;
        }
    }

    #define STAGE(bi, kt) do {                                                                    \
        __builtin_amdgcn_global_load_lds((gbl_vp)(aS + (kt) * 64),                                \
            (lds_vp)&As[bi][t * 16], 16, 0, 0);                                                   \
        __builtin_amdgcn_global_load_lds((gbl_vp)(bS + (kt) * 64),                                \
            (lds_vp)&Bs[bi][t * 16], 16, 0, 0);                                                   \
    } while (0)

    #define COMPUTE(bi) do {                                                                      \
        _Pragma("unroll")                                                                         \
        for (int h = 0; h < 2; ++h) {                                                             \
            long afr = *(const long*)&As[bi][aoff[h]];                                            \
            _Pragma("unroll")                                                                     \
            for (int j = 0; j < 4; ++j) {                                                         \
                long bfr = *(const long*)&Bs[bi][boff[j][h]];                                     \
                acc[j] = __builtin_amdgcn_mfma_f32_16x16x32_fp8_fp8(afr, bfr, acc[j], 0, 0, 0);   \
            }                                                                                     \
        }                                                                                         \
    } while (0)

    int nt = K >> 6;                 // 12 (K=768) or 3 (K=192)
    STAGE(0, 0);
    STAGE(1, 1);
    int bi = 0;
    for (int tt = 0; tt < nt; ++tt) {
        // wait step tt's 2 loads; step tt+1's 2 stay in flight across barrier
        if (tt < nt - 1) asm volatile("s_waitcnt vmcnt(2)\n\ts_barrier" ::: "memory");
        else             asm volatile("s_waitcnt vmcnt(0)\n\ts_barrier" ::: "memory");
        if (tt + 2 < nt) {
            int nb = bi + 2; if (nb >= 3) nb -= 3;
            STAGE(nb, tt + 2);
        }
        COMPUTE(bi);
        ++bi; if (bi == 3) bi = 0;
    }

    #undef STAGE
    #undef COMPUTE

    int rowq = lane >> 4;
    int do_gelu = jb.flags & 1, out_bf = jb.flags & 2, res_bf = jb.flags & 4, out_f8 = jb.flags & 8;
    const void* res = jb.res;
    #pragma unroll
    for (int j = 0; j < 4; ++j) {
        int c = bn + j * 16 + rsel;
        if (c < N) {
            float bias = (c < jb.Nsplit) ? jb.ba[c] : jb.bb[c - jb.Nsplit];
            #pragma unroll
            for (int r4 = 0; r4 < 4; ++r4) {
                int m = bm + wave * 16 + rowq * 4 + r4;
                float v = acc[j][r4] * 0.015625f + bias;   // descale weights x64
                if (do_gelu) v = 0.5f * v * (1.f + erff(v * 0.70710678118f));
                size_t oi = (size_t)m * N + c;
                if (res) v += res_bf ? (float)((const __bf16*)res)[oi]
                                     : ((const float*)res)[oi];
                if (out_f8)      ((unsigned char*)jb.out)[oi] = to_f8(v);
                else if (out_bf) ((__bf16*)jb.out)[oi] = (__bf16)v;
                else             ((float*)jb.out)[oi]  = v;
            }
        }
    }
}

// ---------------------------------------------------------------------------
// Deformable sampling: one wave per (b,q,h); value bf16 in, fp8 out.
// ---------------------------------------------------------------------------
__global__ __launch_bounds__(256)
void sample_kernel(const __bf16* __restrict__ value, const float* __restrict__ offatt,
                   const float* __restrict__ refp, unsigned char* __restrict__ out) {
    int wid  = blockIdx.x * 4 + (threadIdx.x >> 6);
    int lane = threadIdx.x & 63;
    int h  = wid % NH_;
    int bq = wid / NH_;
    int b  = bq / LQ;

    const float* oa = offatt + (size_t)bq * 144;
    float rx = refp[(size_t)bq * 2 + 0] * (float)WW - 0.5f;
    float ry = refp[(size_t)bq * 2 + 1] * (float)HH - 0.5f;

    float l0 = oa[96 + h * 4 + 0], l1 = oa[96 + h * 4 + 1];
    float l2 = oa[96 + h * 4 + 2], l3 = oa[96 + h * 4 + 3];
    float mx = fmaxf(fmaxf(l0, l1), fmaxf(l2, l3));
    float e0 = __expf(l0 - mx), e1 = __expf(l1 - mx);
    float e2 = __expf(l2 - mx), e3 = __expf(l3 - mx);
    float rs = 1.f / (e0 + e1 + e2 + e3);

    int pp = lane >> 4;       // point id
    int g  = lane & 15;       // channel group
    float wpl = (pp == 0) ? e0 : (pp == 1) ? e1 : (pp == 2) ? e2 : e3;
    wpl *= rs;

    const float* oxy = oa + h * 8 + pp * 2;
    float x = rx + oxy[0];
    float y = ry + oxy[1];
    float x0f = floorf(x), y0f = floorf(y);
    float wx1 = x - x0f, wy1 = y - y0f;
    float wx0 = 1.f - wx1, wy0 = 1.f - wy1;
    int x0 = (int)x0f, y0 = (int)y0f;
    int x1 = x0 + 1, y1 = y0 + 1;
    float mx0 = ((unsigned)x0 < (unsigned)WW) ? wx0 : 0.f;
    float mx1 = ((unsigned)x1 < (unsigned)WW) ? wx1 : 0.f;
    float my0 = (((unsigned)y0 < (unsigned)HH) ? wy0 : 0.f) * wpl;
    float my1 = (((unsigned)y1 < (unsigned)HH) ? wy1 : 0.f) * wpl;
    int xc0 = x0 & (WW - 1), xc1 = x1 & (WW - 1);
    int r0 = (y0 & (HH - 1)) << 6, r1 = (y1 & (HH - 1)) << 6;

    const __bf16* vbase = value + (size_t)b * (LQ * CC) + h * DH + g * 4;
    bf16x4 v00 = *(const bf16x4*)(vbase + (size_t)(r0 + xc0) * CC);
    bf16x4 v01 = *(const bf16x4*)(vbase + (size_t)(r0 + xc1) * CC);
    bf16x4 v10 = *(const bf16x4*)(vbase + (size_t)(r1 + xc0) * CC);
    bf16x4 v11 = *(const bf16x4*)(vbase + (size_t)(r1 + xc1) * CC);
    float w00 = mx0 * my0, w01 = mx1 * my0, w10 = mx0 * my1, w11 = mx1 * my1;

    f32x4 acc;
    #pragma unroll
    for (int e = 0; e < 4; ++e)
        acc[e] = w00 * (float)v00[e] + w01 * (float)v01[e]
               + w10 * (float)v10[e] + w11 * (float)v11[e];

    #pragma unroll
    for (int e = 0; e < 4; ++e) {
        acc[e] += __shfl_xor(acc[e], 16, 64);
        acc[e] += __shfl_xor(acc[e], 32, 64);
    }
    if (pp == 0) {
        *(unsigned*)(out + (size_t)bq * CC + h * DH + g * 4) =
            pk4_f8(acc[0], acc[1], acc[2], acc[3]);
    }
}

// ---------------------------------------------------------------------------
// Launch
// ---------------------------------------------------------------------------
extern "C" void kernel_launch(void* const* d_in, const int* in_sizes, int n_in,
                              void* d_out, int out_size, void* d_ws, size_t ws_size,
                              hipStream_t stream) {
    const float* query = (const float*)d_in[0];
    const float* refp  = (const float*)d_in[1];
    const float* feat  = (const float*)d_in[2];
    const float* qn_g  = (const float*)d_in[7];
    const float* qn_b  = (const float*)d_in[8];
    const float* fn_g  = (const float*)d_in[9];
    const float* fn_b  = (const float*)d_in[10];
    const float* Wv    = (const float*)d_in[11];
    const float* bv    = (const float*)d_in[12];
    const float* Woff  = (const float*)d_in[13];
    const float* boff  = (const float*)d_in[14];
    const float* Watt  = (const float*)d_in[15];
    const float* batt  = (const float*)d_in[16];
    const float* Wout  = (const float*)d_in[17];
    const float* bout  = (const float*)d_in[18];
    const float* ffn_g = (const float*)d_in[19];
    const float* ffn_b = (const float*)d_in[20];
    const float* W1    = (const float*)d_in[21];
    const float* b1    = (const float*)d_in[22];
    const float* W2    = (const float*)d_in[23];
    const float* b2    = (const float*)d_in[24];
    float* out = (float*)d_out;

    // workspace layout (byte offsets)
    char* ws = (char*)d_ws;
    unsigned char* Wv8    = (unsigned char*)(ws + 0);        // 589824
    unsigned char* Wcomb8 = (unsigned char*)(ws + 1179648);  // 147456 (192x768)
    unsigned char* Wout8  = (unsigned char*)(ws + 1572864);  // 589824
    unsigned char* W18    = (unsigned char*)(ws + 2752512);  // 147456
    unsigned char* W28    = (unsigned char*)(ws + 3145728);  // 147456
    float*  offatt_f = (float*)(ws + 3670016);               // 9437184
    unsigned char* h1_f8 = (unsigned char*)offatt_f;         // reuse (offatt dead after sample)
    __bf16* value_bf = (__bf16*)(ws + 13107200);             // 25165824
    unsigned char* fn_f8   = (unsigned char*)(ws + 38273024); // 12.6MB
    unsigned char* samp_f8 = fn_f8;                           // reuse (fn dead after value GEMM)
    unsigned char* qn_f8   = (unsigned char*)(ws + 50855936); // 12.6MB
    unsigned char* h_f8    = qn_f8;                           // reuse (qn dead after offatt GEMM)
    __bf16* attn_bf  = (__bf16*)(ws + 63438848);             // 25165824

    dim3 blk(256);

    // 0+1. merged: both input LayerNorms (fp8 out) + fp8 weight prep
    PrepJobs jobs;
    jobs.j[0] = {Wv,   Wv8,             768, 768, 768};
    jobs.j[1] = {Woff, Wcomb8,          768,  96,  96};
    jobs.j[2] = {Watt, Wcomb8 + 96*768, 768,  48,  96};  // comb rows 96..191 (144..191 zero)
    jobs.j[3] = {Wout, Wout8,           768, 768, 768};
    jobs.j[4] = {W1,   W18,             768, 192, 192};
    jobs.j[5] = {W2,   W28,             192, 768, 768};
    ln2p_kernel<<<2 * ROWS + 864, blk, 0, stream>>>(query, qn_g, qn_b, qn_f8,
                                                    feat,  fn_g, fn_b, fn_f8, jobs);

    // 2+3. grouped fp8: offatt = qn @ [Woff|Watt]  AND  value = fn @ Wv + bv
    G64Job joff = {qn_f8, Wcomb8, boff, batt, nullptr, offatt_f,
                   96, CC, 144, 0, 768, 3};
    G64Job jval = {fn_f8, Wv8, bv, bv, nullptr, value_bf,
                   CC, CC, CC, 2, 3072, 12};
    gemm64f8<<<768 + 3072, blk, 0, stream>>>(joff, jval);

    // 4. deformable sampling -> fp8
    sample_kernel<<<ROWS * NH_ / 4, blk, 0, stream>>>(value_bf, offatt_f, refp, samp_f8);

    // 5. attnres = query + samp @ Wout + bout (bf16 out, f32 res)
    G64Job jout5 = {samp_f8, Wout8, bout, bout, query, attn_bf,
                    CC, CC, CC, 2, 3072, 12};
    gemm64f8<<<3072, blk, 0, stream>>>(jout5, jout5);

    // 6. h = LN(attnres) -> fp8
    ln_bf_kernel<<<ROWS, blk, 0, stream>>>(attn_bf, ffn_g, ffn_b, h_f8);

    // 7. h1 = gelu(h @ W1 + b1) -> fp8 (N=192)
    G64Job jw1 = {h_f8, W18, b1, b1, nullptr, h1_f8,
                  HID, CC, HID, 1 | 8, 768, 3};
    gemm64f8<<<768, blk, 0, stream>>>(jw1, jw1);

    // 8. out = attnres + h1 @ W2 + b2 (K=192, f32 out, bf16 res)
    G64Job jw2 = {h1_f8, W28, b2, b2, attn_bf, out,
                  CC, HID, CC, 4, 3072, 12};
    gemm64f8<<<3072, blk, 0, stream>>>(jw2, jw2);
}

// Round 10
// 372.953 us; speedup vs baseline: 1.9756x; 1.0042x over previous
//
#include <hip/hip_runtime.h>
#include <hip/hip_bf16.h>
#include <math.h>

// Problem constants:
//   B=4, Lq=4096, C=768, NH=12, d=64, NP=4, nl=1, H=W=64, Lin=4096, hid=192
#define B_    4
#define LQ    4096
#define CC    768
#define NH_   12
#define DH    64
#define NP_   4
#define HH    64
#define WW    64
#define HID   192
#define ROWS  (B_ * LQ)          // 16384
#define EPS_  1e-5f

typedef __bf16 bf16x8 __attribute__((ext_vector_type(8)));
typedef __bf16 bf16x4 __attribute__((ext_vector_type(4)));
typedef float  f32x4  __attribute__((ext_vector_type(4)));

typedef __attribute__((address_space(3))) void* lds_vp;
typedef const __attribute__((address_space(1))) void* gbl_vp;

// fp8 e4m3 (OCP on gfx950) conversion via v_cvt_pk_fp8_f32 (RNE, saturating)
__device__ __forceinline__ unsigned pk4_f8(float a, float b, float c, float d) {
    unsigned lo, hi;
    asm volatile("v_cvt_pk_fp8_f32 %0, %1, %2" : "=v"(lo) : "v"(a), "v"(b));
    asm volatile("v_cvt_pk_fp8_f32 %0, %1, %2" : "=v"(hi) : "v"(c), "v"(d));
    return (lo & 0xffffu) | (hi << 16);
}
__device__ __forceinline__ unsigned char to_f8(float a) {
    unsigned r;
    asm volatile("v_cvt_pk_fp8_f32 %0, %1, %1" : "=v"(r) : "v"(a));
    return (unsigned char)r;
}

// ---------------------------------------------------------------------------
// Weight prep: f32 [K,N] -> fp8 e4m3 [Npad][K] transposed, values x64.
// ---------------------------------------------------------------------------
struct PrepJob { const float* W; unsigned char* Wt; int K; int N; int Npad; };
struct PrepJobs { PrepJob j[6]; };

// ---------------------------------------------------------------------------
// Reductions: butterfly -> all lanes hold the sum (no broadcast needed)
// ---------------------------------------------------------------------------
__inline__ __device__ float wave_allsum64(float v) {
    #pragma unroll
    for (int o = 1; o < 64; o <<= 1) v += __shfl_xor(v, o, 64);
    return v;
}

// ---------------------------------------------------------------------------
// Merged launch: dual LayerNorm (f32 in, fp8 out, WAVE-PER-ROW, no LDS/bar)
// + fp8 weight prep. blocks [0, 8192): LN (4 rows each); [8192, +864): prep.
// ---------------------------------------------------------------------------
#define LNBLKS (2 * ROWS / 4)    // 8192

__global__ __launch_bounds__(256)
void ln2p_kernel(const float* __restrict__ x0, const float* __restrict__ g0,
                 const float* __restrict__ b0, unsigned char* __restrict__ y0,
                 const float* __restrict__ x1, const float* __restrict__ g1,
                 const float* __restrict__ b1, unsigned char* __restrict__ y1,
                 PrepJobs jobs) {
    int bx = blockIdx.x;
    int t = threadIdx.x;

    if (bx >= LNBLKS) {
        // ---- weight-prep path (fp8 x64) ----
        __shared__ float tile[64][65];
        int tid = bx - LNBLKS;
        PrepJob job = jobs.j[tid / 144];
        int rem = tid % 144;
        int k0 = (rem % 12) * 64, n0 = (rem / 12) * 64;
        if (k0 >= job.K || n0 >= job.Npad) return;
        int c = t & 63, r0 = t >> 6;
        #pragma unroll
        for (int i = 0; i < 16; ++i) {
            int kk = i * 4 + r0;
            float v = 0.f;
            if (k0 + kk < job.K && n0 + c < job.N) v = job.W[(size_t)(k0 + kk) * job.N + n0 + c];
            tile[kk][c] = v;
        }
        __syncthreads();
        #pragma unroll
        for (int i = 0; i < 16; ++i) {
            int nn = i * 4 + r0;
            if (n0 + nn < job.Npad && k0 + c < job.K)
                job.Wt[(size_t)(n0 + nn) * job.K + k0 + c] = to_f8(tile[c][nn] * 64.f);
        }
        return;
    }

    // ---- LayerNorm path: one wave per row, lane owns vec4s {l, l+64, l+128}
    int wv = t >> 6, lane = t & 63;
    int rid = bx * 4 + wv;
    int sel = rid >= ROWS;
    int row = rid - (sel ? ROWS : 0);
    const float* x = sel ? x1 : x0;
    const float* g = sel ? g1 : g0;
    const float* b = sel ? b1 : b0;
    unsigned char* y = sel ? y1 : y0;
    const float* xr = x + (size_t)row * CC;
    unsigned char* yr = y + (size_t)row * CC;

    f32x4 v0 = *(const f32x4*)(xr + 4 * lane);
    f32x4 v1 = *(const f32x4*)(xr + 4 * (lane + 64));
    f32x4 v2 = *(const f32x4*)(xr + 4 * (lane + 128));
    float s = 0.f, s2 = 0.f;
    #pragma unroll
    for (int e = 0; e < 4; ++e) {
        s += v0[e] + v1[e] + v2[e];
        s2 += v0[e]*v0[e] + v1[e]*v1[e] + v2[e]*v2[e];
    }
    float S  = wave_allsum64(s);
    float S2 = wave_allsum64(s2);
    float mean = S / CC;
    float inv  = rsqrtf(S2 / CC - mean * mean + EPS_);

    f32x4 gv0 = *(const f32x4*)(g + 4 * lane);
    f32x4 gv1 = *(const f32x4*)(g + 4 * (lane + 64));
    f32x4 gv2 = *(const f32x4*)(g + 4 * (lane + 128));
    f32x4 bv0 = *(const f32x4*)(b + 4 * lane);
    f32x4 bv1 = *(const f32x4*)(b + 4 * (lane + 64));
    f32x4 bv2 = *(const f32x4*)(b + 4 * (lane + 128));

    float o0[4], o1[4], o2[4];
    #pragma unroll
    for (int e = 0; e < 4; ++e) {
        o0[e] = (v0[e] - mean) * inv * gv0[e] + bv0[e];
        o1[e] = (v1[e] - mean) * inv * gv1[e] + bv1[e];
        o2[e] = (v2[e] - mean) * inv * gv2[e] + bv2[e];
    }
    *(unsigned*)(yr + 4 * lane)         = pk4_f8(o0[0], o0[1], o0[2], o0[3]);
    *(unsigned*)(yr + 4 * (lane + 64))  = pk4_f8(o1[0], o1[1], o1[2], o1[3]);
    *(unsigned*)(yr + 4 * (lane + 128)) = pk4_f8(o2[0], o2[1], o2[2], o2[3]);
}

// ---------------------------------------------------------------------------
// LayerNorm, bf16 in -> fp8 out, WAVE-PER-ROW (4 rows/block, no LDS/barrier).
// Row = 96 bf16x8 chunks: lane l owns chunk l; lanes < 32 also chunk 64+l.
// ---------------------------------------------------------------------------
__global__ __launch_bounds__(256)
void ln_bf_kernel(const __bf16* __restrict__ x, const float* __restrict__ g,
                  const float* __restrict__ b, unsigned char* __restrict__ y) {
    int wv = threadIdx.x >> 6, lane = threadIdx.x & 63;
    int row = blockIdx.x * 4 + wv;
    const __bf16* xr = x + (size_t)row * CC;
    unsigned char* yr = y + (size_t)row * CC;

    bf16x8 c0 = *(const bf16x8*)(xr + lane * 8);
    bf16x8 c1 = {};
    if (lane < 32) c1 = *(const bf16x8*)(xr + 512 + lane * 8);
    float a0[8], a1[8];
    float s = 0.f, s2 = 0.f;
    #pragma unroll
    for (int e = 0; e < 8; ++e) {
        a0[e] = (float)c0[e]; a1[e] = (float)c1[e];
        s += a0[e] + a1[e];
        s2 += a0[e]*a0[e] + a1[e]*a1[e];
    }
    float S  = wave_allsum64(s);
    float S2 = wave_allsum64(s2);
    float mean = S / CC;
    float inv  = rsqrtf(S2 / CC - mean * mean + EPS_);

    {
        f32x4 gl = *(const f32x4*)(g + lane * 8);
        f32x4 gh = *(const f32x4*)(g + lane * 8 + 4);
        f32x4 bl = *(const f32x4*)(b + lane * 8);
        f32x4 bh = *(const f32x4*)(b + lane * 8 + 4);
        float o[8];
        #pragma unroll
        for (int e = 0; e < 4; ++e) {
            o[e]     = (a0[e]     - mean) * inv * gl[e] + bl[e];
            o[e + 4] = (a0[e + 4] - mean) * inv * gh[e] + bh[e];
        }
        uint2 pk;
        pk.x = pk4_f8(o[0], o[1], o[2], o[3]);
        pk.y = pk4_f8(o[4], o[5], o[6], o[7]);
        *(uint2*)(yr + lane * 8) = pk;
    }
    if (lane < 32) {
        f32x4 gl = *(const f32x4*)(g + 512 + lane * 8);
        f32x4 gh = *(const f32x4*)(g + 512 + lane * 8 + 4);
        f32x4 bl = *(const f32x4*)(b + 512 + lane * 8);
        f32x4 bh = *(const f32x4*)(b + 512 + lane * 8 + 4);
        float o[8];
        #pragma unroll
        for (int e = 0; e < 4; ++e) {
            o[e]     = (a1[e]     - mean) * inv * gl[e] + bl[e];
            o[e + 4] = (a1[e + 4] - mean) * inv * gh[e] + bh[e];
        }
        uint2 pk;
        pk.x = pk4_f8(o[0], o[1], o[2], o[3]);
        pk.y = pk4_f8(o[4], o[5], o[6], o[7]);
        *(uint2*)(yr + 512 + lane * 8) = pk;
    }
}

// ---------------------------------------------------------------------------
// Grouped 64x64-tile FP8 MFMA GEMM, BK=64, ONE barrier per K-step
// (3-buffer distance-2 schedule). 24 KB LDS -> 6 blocks/CU.
// Chunk-XOR swizzle (<=4-way aliasing, minimum for 512 B b64 wave read).
// flags: 1 gelu, 2 out bf16, 4 res bf16, 8 out fp8 (else f32 out)
// ---------------------------------------------------------------------------
struct G64Job {
    const unsigned char* A; const unsigned char* Bt;
    const float* ba; const float* bb;
    const void* res; void* out;
    int Nsplit, K, N, flags, nblk, gx;
};

__global__ __launch_bounds__(256, 6)
void gemm64f8(G64Job j0, G64Job j1) {
    __shared__ unsigned char As[3][4096];
    __shared__ unsigned char Bs[3][4096];

    int bid = blockIdx.x;
    G64Job jb = j0;
    if (bid >= j0.nblk) { jb = j1; bid -= j0.nblk; }

    int t = threadIdx.x;
    int lane = t & 63, wave = t >> 6;

    int swz = (bid & 7) * (jb.nblk >> 3) + (bid >> 3);
    int bx = swz % jb.gx, by = swz / jb.gx;
    int bm = by * 64, bn = bx * 64;
    int K = jb.K, N = jb.N;

    f32x4 acc[4] = {};

    // staging: thread t covers row r = t>>2 (0..63), LDS chunk cp = t&3;
    // global chunk gc = cp ^ ((r>>2)&3)  (inverse swizzle, linear LDS dest)
    int r = t >> 2, cp = t & 3;
    int gc = cp ^ ((r >> 2) & 3);
    const unsigned char* aS = jb.A  + (size_t)(bm + r) * K + gc * 16;
    const unsigned char* bS = jb.Bt + (size_t)(bn + r) * K + gc * 16;

    // compute-side swizzled read offsets: row ra, k-half h, lane kq
    int rsel = lane & 15, kq = lane >> 4;
    int ra = wave * 16 + rsel;
    int aoff[2], boff[4][2];
    #pragma unroll
    for (int h = 0; h < 2; ++h) {
        int ch = ((h << 1) | (kq >> 1)) ^ ((ra >> 2) & 3);
        aoff[h] = ra * 64 + ch * 16 + (kq & 1) * 8;
        #pragma unroll
        for (int j = 0; j < 4; ++j) {
            int n = rsel + j * 16;
            int cb = ((h << 1) | (kq >> 1)) ^ ((n >> 2) & 3);
            boff[j][h] = n * 64 + cb * 16 + (kq & 1) * 8;
        }
    }

    #define STAGE(bi, kt) do {                                                                    \
        __builtin_amdgcn_global_load_lds((gbl_vp)(aS + (kt) * 64),                                \
            (lds_vp)&As[bi][t * 16], 16, 0, 0);                                                   \
        __builtin_amdgcn_global_load_lds((gbl_vp)(bS + (kt) * 64),                                \
            (lds_vp)&Bs[bi][t * 16], 16, 0, 0);                                                   \
    } while (0)

    #define COMPUTE(bi) do {                                                                      \
        _Pragma("unroll")                                                                         \
        for (int h = 0; h < 2; ++h) {                                                             \
            long afr = *(const long*)&As[bi][aoff[h]];                                            \
            _Pragma("unroll")                                                                     \
            for (int j = 0; j < 4; ++j) {                                                         \
                long bfr = *(const long*)&Bs[bi][boff[j][h]];                                     \
                acc[j] = __builtin_amdgcn_mfma_f32_16x16x32_fp8_fp8(afr, bfr, acc[j], 0, 0, 0);   \
            }                                                                                     \
        }                                                                                         \
    } while (0)

    int nt = K >> 6;                 // 12 (K=768) or 3 (K=192)
    STAGE(0, 0);
    STAGE(1, 1);
    int bi = 0;
    for (int tt = 0; tt < nt; ++tt) {
        // wait step tt's 2 loads; step tt+1's 2 stay in flight across barrier
        if (tt < nt - 1) asm volatile("s_waitcnt vmcnt(2)\n\ts_barrier" ::: "memory");
        else             asm volatile("s_waitcnt vmcnt(0)\n\ts_barrier" ::: "memory");
        if (tt + 2 < nt) {
            int nb = bi + 2; if (nb >= 3) nb -= 3;
            STAGE(nb, tt + 2);
        }
        COMPUTE(bi);
        ++bi; if (bi == 3) bi = 0;
    }

    #undef STAGE
    #undef COMPUTE

    int rowq = lane >> 4;
    int do_gelu = jb.flags & 1, out_bf = jb.flags & 2, res_bf = jb.flags & 4, out_f8 = jb.flags & 8;
    const void* res = jb.res;
    #pragma unroll
    for (int j = 0; j < 4; ++j) {
        int c = bn + j * 16 + rsel;
        if (c < N) {
            float bias = (c < jb.Nsplit) ? jb.ba[c] : jb.bb[c - jb.Nsplit];
            #pragma unroll
            for (int r4 = 0; r4 < 4; ++r4) {
                int m = bm + wave * 16 + rowq * 4 + r4;
                float v = acc[j][r4] * 0.015625f + bias;   // descale weights x64
                if (do_gelu) v = 0.5f * v * (1.f + erff(v * 0.70710678118f));
                size_t oi = (size_t)m * N + c;
                if (res) v += res_bf ? (float)((const __bf16*)res)[oi]
                                     : ((const float*)res)[oi];
                if (out_f8)      ((unsigned char*)jb.out)[oi] = to_f8(v);
                else if (out_bf) ((__bf16*)jb.out)[oi] = (__bf16)v;
                else             ((float*)jb.out)[oi]  = v;
            }
        }
    }
}

// ---------------------------------------------------------------------------
// Deformable sampling: one wave per (b,q,h); value bf16 in, fp8 out.
// ---------------------------------------------------------------------------
__global__ __launch_bounds__(256)
void sample_kernel(const __bf16* __restrict__ value, const float* __restrict__ offatt,
                   const float* __restrict__ refp, unsigned char* __restrict__ out) {
    int wid  = blockIdx.x * 4 + (threadIdx.x >> 6);
    int lane = threadIdx.x & 63;
    int h  = wid % NH_;
    int bq = wid / NH_;
    int b  = bq / LQ;

    const float* oa = offatt + (size_t)bq * 144;
    float rx = refp[(size_t)bq * 2 + 0] * (float)WW - 0.5f;
    float ry = refp[(size_t)bq * 2 + 1] * (float)HH - 0.5f;

    float l0 = oa[96 + h * 4 + 0], l1 = oa[96 + h * 4 + 1];
    float l2 = oa[96 + h * 4 + 2], l3 = oa[96 + h * 4 + 3];
    float mx = fmaxf(fmaxf(l0, l1), fmaxf(l2, l3));
    float e0 = __expf(l0 - mx), e1 = __expf(l1 - mx);
    float e2 = __expf(l2 - mx), e3 = __expf(l3 - mx);
    float rs = 1.f / (e0 + e1 + e2 + e3);

    int pp = lane >> 4;       // point id
    int g  = lane & 15;       // channel group
    float wpl = (pp == 0) ? e0 : (pp == 1) ? e1 : (pp == 2) ? e2 : e3;
    wpl *= rs;

    const float* oxy = oa + h * 8 + pp * 2;
    float x = rx + oxy[0];
    float y = ry + oxy[1];
    float x0f = floorf(x), y0f = floorf(y);
    float wx1 = x - x0f, wy1 = y - y0f;
    float wx0 = 1.f - wx1, wy0 = 1.f - wy1;
    int x0 = (int)x0f, y0 = (int)y0f;
    int x1 = x0 + 1, y1 = y0 + 1;
    float mx0 = ((unsigned)x0 < (unsigned)WW) ? wx0 : 0.f;
    float mx1 = ((unsigned)x1 < (unsigned)WW) ? wx1 : 0.f;
    float my0 = (((unsigned)y0 < (unsigned)HH) ? wy0 : 0.f) * wpl;
    float my1 = (((unsigned)y1 < (unsigned)HH) ? wy1 : 0.f) * wpl;
    int xc0 = x0 & (WW - 1), xc1 = x1 & (WW - 1);
    int r0 = (y0 & (HH - 1)) << 6, r1 = (y1 & (HH - 1)) << 6;

    const __bf16* vbase = value + (size_t)b * (LQ * CC) + h * DH + g * 4;
    bf16x4 v00 = *(const bf16x4*)(vbase + (size_t)(r0 + xc0) * CC);
    bf16x4 v01 = *(const bf16x4*)(vbase + (size_t)(r0 + xc1) * CC);
    bf16x4 v10 = *(const bf16x4*)(vbase + (size_t)(r1 + xc0) * CC);
    bf16x4 v11 = *(const bf16x4*)(vbase + (size_t)(r1 + xc1) * CC);
    float w00 = mx0 * my0, w01 = mx1 * my0, w10 = mx0 * my1, w11 = mx1 * my1;

    f32x4 acc;
    #pragma unroll
    for (int e = 0; e < 4; ++e)
        acc[e] = w00 * (float)v00[e] + w01 * (float)v01[e]
               + w10 * (float)v10[e] + w11 * (float)v11[e];

    #pragma unroll
    for (int e = 0; e < 4; ++e) {
        acc[e] += __shfl_xor(acc[e], 16, 64);
        acc[e] += __shfl_xor(acc[e], 32, 64);
    }
    if (pp == 0) {
        *(unsigned*)(out + (size_t)bq * CC + h * DH + g * 4) =
            pk4_f8(acc[0], acc[1], acc[2], acc[3]);
    }
}

// ---------------------------------------------------------------------------
// Launch
// ---------------------------------------------------------------------------
extern "C" void kernel_launch(void* const* d_in, const int* in_sizes, int n_in,
                              void* d_out, int out_size, void* d_ws, size_t ws_size,
                              hipStream_t stream) {
    const float* query = (const float*)d_in[0];
    const float* refp  = (const float*)d_in[1];
    const float* feat  = (const float*)d_in[2];
    const float* qn_g  = (const float*)d_in[7];
    const float* qn_b  = (const float*)d_in[8];
    const float* fn_g  = (const float*)d_in[9];
    const float* fn_b  = (const float*)d_in[10];
    const float* Wv    = (const float*)d_in[11];
    const float* bv    = (const float*)d_in[12];
    const float* Woff  = (const float*)d_in[13];
    const float* boff  = (const float*)d_in[14];
    const float* Watt  = (const float*)d_in[15];
    const float* batt  = (const float*)d_in[16];
    const float* Wout  = (const float*)d_in[17];
    const float* bout  = (const float*)d_in[18];
    const float* ffn_g = (const float*)d_in[19];
    const float* ffn_b = (const float*)d_in[20];
    const float* W1    = (const float*)d_in[21];
    const float* b1    = (const float*)d_in[22];
    const float* W2    = (const float*)d_in[23];
    const float* b2    = (const float*)d_in[24];
    float* out = (float*)d_out;

    // workspace layout (byte offsets)
    char* ws = (char*)d_ws;
    unsigned char* Wv8    = (unsigned char*)(ws + 0);        // 589824
    unsigned char* Wcomb8 = (unsigned char*)(ws + 1179648);  // 147456 (192x768)
    unsigned char* Wout8  = (unsigned char*)(ws + 1572864);  // 589824
    unsigned char* W18    = (unsigned char*)(ws + 2752512);  // 147456
    unsigned char* W28    = (unsigned char*)(ws + 3145728);  // 147456
    float*  offatt_f = (float*)(ws + 3670016);               // 9437184
    unsigned char* h1_f8 = (unsigned char*)offatt_f;         // reuse (offatt dead after sample)
    __bf16* value_bf = (__bf16*)(ws + 13107200);             // 25165824
    unsigned char* fn_f8   = (unsigned char*)(ws + 38273024); // 12.6MB
    unsigned char* samp_f8 = fn_f8;                           // reuse (fn dead after value GEMM)
    unsigned char* qn_f8   = (unsigned char*)(ws + 50855936); // 12.6MB
    unsigned char* h_f8    = qn_f8;                           // reuse (qn dead after offatt GEMM)
    __bf16* attn_bf  = (__bf16*)(ws + 63438848);             // 25165824

    dim3 blk(256);

    // 0+1. merged: both input LayerNorms (fp8 out, wave-per-row) + fp8 prep
    PrepJobs jobs;
    jobs.j[0] = {Wv,   Wv8,             768, 768, 768};
    jobs.j[1] = {Woff, Wcomb8,          768,  96,  96};
    jobs.j[2] = {Watt, Wcomb8 + 96*768, 768,  48,  96};  // comb rows 96..191 (144..191 zero)
    jobs.j[3] = {Wout, Wout8,           768, 768, 768};
    jobs.j[4] = {W1,   W18,             768, 192, 192};
    jobs.j[5] = {W2,   W28,             192, 768, 768};
    ln2p_kernel<<<LNBLKS + 864, blk, 0, stream>>>(query, qn_g, qn_b, qn_f8,
                                                  feat,  fn_g, fn_b, fn_f8, jobs);

    // 2+3. grouped fp8: offatt = qn @ [Woff|Watt]  AND  value = fn @ Wv + bv
    G64Job joff = {qn_f8, Wcomb8, boff, batt, nullptr, offatt_f,
                   96, CC, 144, 0, 768, 3};
    G64Job jval = {fn_f8, Wv8, bv, bv, nullptr, value_bf,
                   CC, CC, CC, 2, 3072, 12};
    gemm64f8<<<768 + 3072, blk, 0, stream>>>(joff, jval);

    // 4. deformable sampling -> fp8
    sample_kernel<<<ROWS * NH_ / 4, blk, 0, stream>>>(value_bf, offatt_f, refp, samp_f8);

    // 5. attnres = query + samp @ Wout + bout (bf16 out, f32 res)
    G64Job jout5 = {samp_f8, Wout8, bout, bout, query, attn_bf,
                    CC, CC, CC, 2, 3072, 12};
    gemm64f8<<<3072, blk, 0, stream>>>(jout5, jout5);

    // 6. h = LN(attnres) -> fp8 (wave-per-row)
    ln_bf_kernel<<<ROWS / 4, blk, 0, stream>>>(attn_bf, ffn_g, ffn_b, h_f8);

    // 7. h1 = gelu(h @ W1 + b1) -> fp8 (N=192)
    G64Job jw1 = {h_f8, W18, b1, b1, nullptr, h1_f8,
                  HID, CC, HID, 1 | 8, 768, 3};
    gemm64f8<<<768, blk, 0, stream>>>(jw1, jw1);

    // 8. out = attnres + h1 @ W2 + b2 (K=192, f32 out, bf16 res)
    G64Job jw2 = {h1_f8, W28, b2, b2, attn_bf, out,
                  CC, HID, CC, 4, 3072, 12};
    gemm64f8<<<3072, blk, 0, stream>>>(jw2, jw2);
}